// Round 19
// baseline (1626.275 us; speedup 1.0000x reference)
//
#include <hip/hip_runtime.h>
#include <hip/hip_fp16.h>
#include <cstdint>
#include <cstddef>

// Problem constants (from reference)
#define NATOM 262144
#define MEDGE 1048576
#define NCRY  32768
// ORIG=200, AF=64, NF=32, GH=16, H=128, NG=3

typedef __attribute__((ext_vector_type(8))) short short8v;   // 8 bf16 (4 VGPR)
typedef __attribute__((ext_vector_type(4))) float f32x4;     // MFMA acc

__device__ __forceinline__ float4 ld4(const float* p){ return *reinterpret_cast<const float4*>(p); }

__device__ __forceinline__ float softplusf_(float x){
  return fmaxf(x, 0.0f) + log1pf(expf(-fabsf(x)));
}
__device__ __forceinline__ float softplus_fast(float x){
  return fmaxf(x, 0.0f) + __logf(1.0f + __expf(-fabsf(x)));
}
__device__ __forceinline__ float sigmoid_fast(float y){
  return __builtin_amdgcn_rcpf(1.0f + __expf(-y));
}

__device__ __forceinline__ unsigned short rne_bf16(float f){
  unsigned u = __float_as_uint(f);
  unsigned r = u + 0x7FFFu + ((u >> 16) & 1u);
  return (unsigned short)(r >> 16);
}
__device__ __forceinline__ float bfu(unsigned short s){
  return __uint_as_float(((unsigned)s) << 16);
}

// monotonic float<->uint key for atomicMax-based segment max
__device__ __forceinline__ unsigned fkey(float x){
  unsigned b = __float_as_uint(x);
  return (b & 0x80000000u) ? ~b : (b | 0x80000000u);
}
__device__ __forceinline__ float fkeyinv(unsigned k){
  unsigned b = (k & 0x80000000u) ? (k & 0x7fffffffu) : ~k;
  return __uint_as_float(b);
}

// async global->LDS 16B copy (dest: wave-uniform base + lane*16 implicit)
__device__ __forceinline__ void gll16(const void* g, void* l){
  __builtin_amdgcn_global_load_lds((const __attribute__((address_space(1))) unsigned*)g,
                                   (__attribute__((address_space(3))) unsigned*)l, 16, 0, 0);
}

// RNE hi/lo split: a ~= bfu(h) + bfu(l)
__device__ __forceinline__ void rne_split(float a, unsigned short& h, unsigned short& l){
  h = rne_bf16(a);
  l = rne_bf16(a - bfu(h));
}

// ---------------------------------------------------------------- stats staging
#define CSB 32
__global__ __launch_bounds__(256) void colstage(const float* __restrict__ part,
                                                float* __restrict__ part2, int nb){
  int t = threadIdx.x;
  int rpb = nb / CSB;
  const float* p = part + (size_t)blockIdx.x*rpb*256 + t;
  float s = 0.f;
  #pragma unroll 4
  for (int r = 0; r < rpb; ++r) s += p[(size_t)r*256];
  part2[blockIdx.x*256 + t] = s;
}

// ---------------------------------------------------------------- edge sort by self atom (counting sort)
__global__ __launch_bounds__(256) void hist_kernel(const int* __restrict__ sidx, int* __restrict__ cnti){
  for (int m = blockIdx.x*256 + threadIdx.x; m < MEDGE; m += gridDim.x*256)
    atomicAdd(&cnti[sidx[m]], 1);
}

__global__ __launch_bounds__(256) void scan1(const int* __restrict__ cnti,
                                             int* __restrict__ loc, int* __restrict__ bsum){
  __shared__ int sm[256];
  int t = threadIdx.x;
  int v = cnti[blockIdx.x*256 + t];
  sm[t] = v;
  __syncthreads();
  for (int off = 1; off < 256; off <<= 1){
    int x = (t >= off) ? sm[t-off] : 0;
    __syncthreads();
    sm[t] += x;
    __syncthreads();
  }
  loc[blockIdx.x*256 + t] = sm[t] - v;     // exclusive
  if (t == 255) bsum[blockIdx.x] = sm[255];
}

__global__ __launch_bounds__(256) void scan2(int* __restrict__ bsum){
  __shared__ int sm[256];
  int t = threadIdx.x;
  int v0 = bsum[t*4+0], v1 = bsum[t*4+1], v2 = bsum[t*4+2], v3 = bsum[t*4+3];
  int tot = v0+v1+v2+v3;
  sm[t] = tot;
  __syncthreads();
  for (int off = 1; off < 256; off <<= 1){
    int x = (t >= off) ? sm[t-off] : 0;
    __syncthreads();
    sm[t] += x;
    __syncthreads();
  }
  int te = sm[t] - tot;
  bsum[t*4+0] = te;
  bsum[t*4+1] = te + v0;
  bsum[t*4+2] = te + v0 + v1;
  bsum[t*4+3] = te + v0 + v1 + v2;
}

__global__ __launch_bounds__(256) void scan3(const int* __restrict__ loc, const int* __restrict__ bsum,
                                             int* __restrict__ base){
  int i = blockIdx.x*256 + threadIdx.x;
  base[i] = loc[i] + bsum[i >> 8];
}

__global__ __launch_bounds__(256) void recip_int(const int* __restrict__ cnti, float* __restrict__ recip){
  int n = blockIdx.x*256 + threadIdx.x;
  if (n < NATOM) recip[n] = 1.0f / fmaxf((float)cnti[n], 1.0f);
}

// rank & permute: sidx_s/nidx_s sorted by self atom; nbr fea converted bf16 + permuted
__global__ __launch_bounds__(256) void rank_kernel(const int* __restrict__ sidx, const int* __restrict__ nidx,
                                                   const int* __restrict__ base, int* __restrict__ ctr,
                                                   const float* __restrict__ nbr,
                                                   int* __restrict__ sidx_s, int* __restrict__ nidx_s,
                                                   short* __restrict__ feap){
  for (int m = blockIdx.x*256 + threadIdx.x; m < MEDGE; m += gridDim.x*256){
    int s = sidx[m];
    int p = base[s] + atomicAdd(&ctr[s], 1);
    sidx_s[p] = s;
    nidx_s[p] = nidx[m];
    const float* src = nbr + (size_t)m*32;
    uint4* dst = (uint4*)(feap + (size_t)p*32);
    #pragma unroll
    for (int c = 0; c < 4; ++c){
      float4 a = ld4(src + c*8), b = ld4(src + c*8 + 4);
      float fv[8] = {a.x,a.y,a.z,a.w,b.x,b.y,b.z,b.w};
      unsigned w[4];
      #pragma unroll
      for (int i=0;i<4;i++)
        w[i] = (unsigned)rne_bf16(fv[2*i]) | ((unsigned)rne_bf16(fv[2*i+1]) << 16);
      dst[c] = make_uint4(w[0],w[1],w[2],w[3]);
    }
  }
}

// ---------------------------------------------------------------- embed W prep
__global__ __launch_bounds__(256) void wprep_embed(const float* __restrict__ embW,
                                                   short* __restrict__ Weh, short* __restrict__ Wel){
  int idx = blockIdx.x*256 + threadIdx.x;   // 64*224 = 14336
  if (idx >= 64*224) return;
  int k = idx % 224, c = idx / 224;
  float w = (k < 200) ? embW[(size_t)k*64 + c] : 0.0f;
  unsigned short h, l;
  rne_split(w, h, l);
  Weh[idx] = (short)h;
  Wel[idx] = (short)l;
}

// ---------------------------------------------------------------- embedding via split-bf16 MFMA
__global__ __launch_bounds__(256) void embed_mfma(const float* __restrict__ orig,
                                                  const short* __restrict__ Weh,
                                                  const short* __restrict__ Wel,
                                                  const float* __restrict__ bias,
                                                  short* __restrict__ atom_h,
                                                  short* __restrict__ atom_l){
  __shared__ uint4 ab4[3208];   // 51328 B
  char* ab = (char*)ab4;
  int t = threadIdx.x, lane = t & 63, wid = t >> 6;
  int r16 = lane & 15, g = lane >> 4;
  int col = wid*16 + r16;

  short8v Bh[7], Bl[7];
  #pragma unroll
  for (int ks = 0; ks < 7; ks++){
    int o = col*224 + ks*32 + g*8;
    Bh[ks] = *(const short8v*)(Weh + o);
    Bl[ks] = *(const short8v*)(Wel + o);
  }
  float bv = bias[col];
  int n0 = blockIdx.x * 64;
  const char* src = (const char*)orig + (size_t)n0*800;
  #pragma unroll
  for (int i = 0; i < 13; i++){
    int j = wid + i*4;
    if (j < 50) gll16(src + j*1024 + lane*16, ab + j*1024);
  }
  __syncthreads();

  #pragma unroll
  for (int grp = 0; grp < 4; grp++){
    f32x4 acc = {bv, bv, bv, bv};
    const char* arow = ab + (grp*16 + r16)*800;
    #pragma unroll
    for (int ks = 0; ks < 7; ks++){
      short8v ah, al;
      if (ks < 6 || g == 0){
        const float* f = (const float*)(arow + ks*128 + g*32);
        float4 f0 = *(const float4*)f, f1 = *(const float4*)(f+4);
        float fv[8] = {f0.x,f0.y,f0.z,f0.w,f1.x,f1.y,f1.z,f1.w};
        unsigned hw[4], lw[4];
        #pragma unroll
        for (int p = 0; p < 4; p++){
          unsigned short h0, l0, h1, l1;
          rne_split(fv[2*p], h0, l0);
          rne_split(fv[2*p+1], h1, l1);
          hw[p] = (unsigned)h0 | ((unsigned)h1 << 16);
          lw[p] = (unsigned)l0 | ((unsigned)l1 << 16);
        }
        ah = __builtin_bit_cast(short8v, make_uint4(hw[0],hw[1],hw[2],hw[3]));
        al = __builtin_bit_cast(short8v, make_uint4(lw[0],lw[1],lw[2],lw[3]));
      } else {
        ah = (short8v)0; al = (short8v)0;
      }
      acc = __builtin_amdgcn_mfma_f32_16x16x32_bf16(ah, Bh[ks], acc, 0, 0, 0);
      acc = __builtin_amdgcn_mfma_f32_16x16x32_bf16(al, Bh[ks], acc, 0, 0, 0);
      acc = __builtin_amdgcn_mfma_f32_16x16x32_bf16(ah, Bl[ks], acc, 0, 0, 0);
    }
    int rowb = n0 + grp*16 + g*4;
    #pragma unroll
    for (int r = 0; r < 4; r++){
      float a = acc[r];
      unsigned short h, l;
      rne_split(a, h, l);
      size_t off = (size_t)(rowb + r)*64 + col;
      atom_h[off] = (short)h;
      atom_l[off] = (short)l;
    }
  }
}

// ---------------------------------------------------------------- W prep (edge)
__global__ __launch_bounds__(256) void wprep(const float* __restrict__ filtW, const float* __restrict__ coreW,
                                             short* __restrict__ Wth, short* __restrict__ Wtl){
  int idx = blockIdx.x*256 + threadIdx.x;   // 3*128*160 = 61440
  if (idx >= 3*128*160) return;
  int k = idx % 160; int rest = idx / 160; int c = rest & 127; int layer = rest >> 7;
  float w = (c < 64) ? filtW[((size_t)layer*160 + k)*64 + c] : coreW[((size_t)layer*160 + k)*64 + (c-64)];
  unsigned short h, l;
  rne_split(w, h, l);
  Wth[idx] = (short)h;
  Wtl[idx] = (short)l;
}

// ---------------------------------------------------------------- edge GEMM: 2-phase gll pipeline, TILE=32
// LDS: 28 cols x 32 edges x 16B = 14KB/buffer (28KB total -> 5 blocks/CU).
// cols: 0-7 self_h, 8-15 nbr_h, 16-19 fea, 20-27 self_l  (nbr lo + fea lo dropped, RNE-unbiased).
// PASS0 optionally writes ycache fp16: unit8B idx = (e>>2)*128 + col, elem (e&3).
#define NT_PER_BLK 8

#define MFMA_B(A,B,ACC) ACC = __builtin_amdgcn_mfma_f32_16x16x32_bf16(A, B, ACC, 0, 0, 0)

template<int PASS>
__global__ __launch_bounds__(256) void edge_mfma(
    const short* __restrict__ atom_h, const short* __restrict__ atom_l,
    const short* __restrict__ nbr_h,
    const int* __restrict__ sidx, const int* __restrict__ nidx,
    const short* __restrict__ Wth, const short* __restrict__ Wtl,
    const float* __restrict__ bfp, const float* __restrict__ bcp,
    const float* __restrict__ scale, const float* __restrict__ shift,
    float* __restrict__ partial,
    float* __restrict__ meanacc,
    unsigned short* __restrict__ ycache)
{
  __shared__ uint4 xb[2][28*32];   // 2 x 14 KB
  int t = threadIdx.x, lane = t & 63, wid = t >> 6;   // 4 waves
  int r16 = lane & 15, g = lane >> 4;
  int colf = wid*16 + r16, colc = colf + 64;
  int el = lane & 31;

  short8v Bhf[5], Blf[5], Bhc[5], Blc[5];
  {
    const short* wfh = Wth + colf*160;
    const short* wch = Wth + colc*160;
    const short* wfl = Wtl + colf*160;
    const short* wcl = Wtl + colc*160;
    #pragma unroll
    for (int ks = 0; ks < 5; ks++){
      int o = ks*32 + g*8;
      Bhf[ks] = *(const short8v*)(wfh + o);
      Bhc[ks] = *(const short8v*)(wch + o);
      Blf[ks] = *(const short8v*)(wfl + o);
      Blc[ks] = *(const short8v*)(wcl + o);
    }
  }
  float bfv = bfp[colf], bcv = bcp[colf];
  float sf = 0.f, hf = 0.f, sc = 0.f, hc = 0.f;
  if (PASS == 1){ sf = scale[colf]; hf = shift[colf]; sc = scale[colc]; hc = shift[colc]; }
  float s0 = 0.f, q0 = 0.f, s1 = 0.f, q1 = 0.f;

  int tile0 = blockIdx.x * NT_PER_BLK;

  #define STAGE(BUF, TILE, SE, NE)                                              \
  {                                                                             \
    uint4* dst = (uint4*)(BUF);                                                 \
    int e0s_ = (TILE)*32;                                                       \
    _Pragma("unroll")                                                           \
    for (int j = wid; j < 14; j += 4){                                          \
      int c = 2*j + (lane >> 5);                                                \
      const short* src;                                                         \
      if      (c < 8)  src = atom_h + (size_t)(SE)*64 + c*8;                    \
      else if (c < 16) src = atom_h + (size_t)(NE)*64 + (c-8)*8;                \
      else if (c < 20) src = nbr_h + (size_t)(e0s_+el)*32 + (c-16)*8;           \
      else             src = atom_l + (size_t)(SE)*64 + (c-20)*8;               \
      gll16(src, dst + j*64);                                                   \
    }                                                                           \
  }

  int se, ne;
  { int e = tile0*32 + el; se = sidx[e]; ne = nidx[e]; }
  STAGE(xb[0], tile0, se, ne);
  { int e = (tile0+1)*32 + el; se = sidx[e]; ne = nidx[e]; }

  for (int tt = 0; tt < NT_PER_BLK; ++tt){
    asm volatile("s_waitcnt vmcnt(0)" ::: "memory");
    __builtin_amdgcn_s_barrier();           // LDS tile tt ready for all waves
    if (tt+1 < NT_PER_BLK){
      STAGE(xb[(tt+1)&1], tile0+tt+1, se, ne);
      if (tt+2 < NT_PER_BLK){ int e = (tile0+tt+2)*32 + el; se = sidx[e]; ne = nidx[e]; }
    }
    int e0 = (tile0+tt)*32;
    const char* buf = (const char*)xb[tt & 1];
    #pragma unroll
    for (int grp = 0; grp < 2; ++grp){
      f32x4 accf = {bfv,bfv,bfv,bfv}, accc = {bcv,bcv,bcv,bcv};
      const char* base = buf + (grp*16 + r16)*16;
      #pragma unroll
      for (int ks = 0; ks < 5; ++ks){
        short8v ah = *(const short8v*)(base + (ks*4+g)*512);
        MFMA_B(ah, Bhf[ks], accf); MFMA_B(ah, Bhc[ks], accc);
        MFMA_B(ah, Blf[ks], accf); MFMA_B(ah, Blc[ks], accc);
        if (ks < 2){
          short8v al = *(const short8v*)(base + (20+ks*4+g)*512);
          MFMA_B(al, Bhf[ks], accf); MFMA_B(al, Bhc[ks], accc);
        }
      }
      if (PASS == 0){
        #pragma unroll
        for (int r = 0; r < 4; r++){
          float yf = accf[r], yc = accc[r];
          s0 += yf; q0 += yf*yf; s1 += yc; q1 += yc*yc;
        }
        if (ycache){
          int ebase = e0 + grp*16 + g*4;         // 4 consecutive edges, 4-aligned
          uint2 pf, pc;
          #pragma unroll
          for (int r = 0; r < 4; r++){
            ((__half*)&pf)[r] = __float2half_rn(accf[r]);
            ((__half*)&pc)[r] = __float2half_rn(accc[r]);
          }
          uint2* yrow = (uint2*)ycache + (size_t)(ebase >> 2)*128;
          yrow[colf]      = pf;
          yrow[64 + colf] = pc;
        }
      } else {
        // sorted edges: run-compress atomics (thread's 4 edges are consecutive)
        int ebase = e0 + grp*16 + g*4;
        int a_prev = sidx[ebase];
        float accum = 0.f;
        #pragma unroll
        for (int r = 0; r < 4; r++){
          float f  = sigmoid_fast(accf[r]*sf + hf);
          float c2 = softplus_fast(accc[r]*sc + hc);
          int a = sidx[ebase + r];
          if (a != a_prev){
            atomicAdd(&meanacc[(size_t)a_prev*64 + colf], accum);
            accum = 0.f;
            a_prev = a;
          }
          accum += f*c2;
        }
        atomicAdd(&meanacc[(size_t)a_prev*64 + colf], accum);
      }
    }
  }
  #undef STAGE

  if (PASS == 0){
    s0 += __shfl_xor(s0,16); s0 += __shfl_xor(s0,32);
    q0 += __shfl_xor(q0,16); q0 += __shfl_xor(q0,32);
    s1 += __shfl_xor(s1,16); s1 += __shfl_xor(s1,32);
    q1 += __shfl_xor(q1,16); q1 += __shfl_xor(q1,32);
    __syncthreads();
    float* scm = (float*)&xb[0][0];
    if (g == 0)
      *(float4*)&scm[(wid*16 + r16)*4] = make_float4(s0, q0, s1, q1);
    __syncthreads();
    {
      int stat = t >> 7, colx = t & 127;
      int isc = (colx >= 64) ? 1 : 0;
      int cc = colx & 63;
      int v = isc*2 + stat;
      partial[(size_t)blockIdx.x*256 + stat*128 + colx] = scm[((cc>>4)*16 + (cc&15))*4 + v];
    }
  }
}

// ---------------------------------------------------------------- fused segment-mean + BN-o stats from ycache
__global__ __launch_bounds__(256) void aggregate(const unsigned short* __restrict__ ycache,
                                                 const int* __restrict__ base,
                                                 const int* __restrict__ cnti,
                                                 const float* __restrict__ scale,
                                                 const float* __restrict__ shift,
                                                 float* __restrict__ meanacc,
                                                 float* __restrict__ partial){
  int t = threadIdx.x, j = t & 63, w = t >> 6;
  float sf = scale[j], hf = shift[j];
  float sc = scale[j+64], hc = shift[j+64];
  float s = 0.f, q = 0.f;
  int n0 = blockIdx.x*128 + w*32;        // grid 2048 -> 128 atoms/block, 32/wave
  for (int i = 0; i < 32; ++i){
    int n = n0 + i;
    int b0 = base[n], deg = cnti[n];
    float acc = 0.f;
    if (deg > 0){
      int q0 = b0 >> 2, q1 = (b0 + deg + 3) >> 2;
      for (int qq = q0; qq < q1; ++qq){
        const uint2* yrow = (const uint2*)ycache + (size_t)qq*128;
        uint2 f4 = yrow[j], c4 = yrow[64 + j];
        int e0 = qq*4;
        #pragma unroll
        for (int r = 0; r < 4; ++r){
          int e = e0 + r;
          if (e >= b0 && e < b0 + deg){
            float yf = __half2float(((const __half*)&f4)[r]);
            float yc = __half2float(((const __half*)&c4)[r]);
            acc += sigmoid_fast(yf*sf + hf) * softplus_fast(yc*sc + hc);
          }
        }
      }
    }
    float mean = acc / fmaxf((float)deg, 1.0f);
    meanacc[(size_t)n*64 + j] = mean;
    s += mean; q += mean*mean;
  }
  __shared__ float red[4][128];
  red[w][j] = s; red[w][64+j] = q;
  __syncthreads();
  if (t < 64){
    partial[(size_t)blockIdx.x*256 + t]       = red[0][t]+red[1][t]+red[2][t]+red[3][t];
    partial[(size_t)blockIdx.x*256 + 128 + t] = red[0][64+t]+red[1][64+t]+red[2][64+t]+red[3][64+t];
  }
}

// ---------------------------------------------------------------- BN finalize (reads part2)
__global__ void bnfin_kernel(int nf, float invcnt, const float* __restrict__ p2,
                             const float* __restrict__ g, const float* __restrict__ b,
                             float* __restrict__ scale, float* __restrict__ shift){
  int j = threadIdx.x;
  if (j >= nf) return;
  float s = 0.f, q = 0.f;
  #pragma unroll 4
  for (int r = 0; r < CSB; ++r){
    s += p2[r*256 + j];
    q += p2[r*256 + 128 + j];
  }
  float m = s*invcnt;
  float v = fmaxf(q*invcnt - m*m, 0.0f);
  float is = rsqrtf(v + 1e-5f);
  float sc = g[j]*is;
  scale[j] = sc;
  shift[j] = b[j] - m*sc;
}

__global__ void bnfin2_kernel(float invcnt, const float* __restrict__ p2,
                              const float* __restrict__ g0, const float* __restrict__ b0,
                              const float* __restrict__ g1, const float* __restrict__ b1,
                              float* __restrict__ scale, float* __restrict__ shift){
  int j = threadIdx.x;   // 128
  float s = 0.f, q = 0.f;
  #pragma unroll 4
  for (int r = 0; r < CSB; ++r){
    s += p2[r*256 + j];
    q += p2[r*256 + 128 + j];
  }
  float m = s*invcnt;
  float v = fmaxf(q*invcnt - m*m, 0.0f);
  float is = rsqrtf(v + 1e-5f);
  float gg = (j < 64) ? g0[j] : g1[j-64];
  float bb = (j < 64) ? b0[j] : b1[j-64];
  float sc = gg*is;
  scale[j] = sc;
  shift[j] = bb - m*sc;
}

// ---------------------------------------------------------------- stats of mean = meanacc * recip (fallback path)
__global__ __launch_bounds__(256) void meanbn_stats(const float* __restrict__ recip,
                                                    const float* __restrict__ meanacc,
                                                    float* __restrict__ partial){
  int t = threadIdx.x;
  float s = 0.f, q = 0.f;
  for (size_t idx = (size_t)blockIdx.x*256 + t; idx < (size_t)NATOM*64; idx += (size_t)gridDim.x*256){
    int n = (int)(idx >> 6);
    float v = meanacc[idx]*recip[n];
    s += v; q += v*v;
  }
  __shared__ float red[256][2];
  red[t][0]=s; red[t][1]=q;
  __syncthreads();
  if (t < 64){
    for (int i=1;i<4;i++){ s += red[t+64*i][0]; q += red[t+64*i][1]; }
    partial[(size_t)blockIdx.x*256 + t]       = s;
    partial[(size_t)blockIdx.x*256 + 128 + t] = q;
  }
}

// atom = softplus(atom + mean*scale + shift), vectorized 4 cols/thread
template<int PREMUL>
__global__ __launch_bounds__(256) void atom_update(short* __restrict__ atom_h,
                                                   short* __restrict__ atom_l,
                                                   const float* __restrict__ meanacc,
                                                   const float* __restrict__ recip,
                                                   const float* __restrict__ scale,
                                                   const float* __restrict__ shift){
  for (size_t idx = (size_t)blockIdx.x*256 + threadIdx.x; idx < (size_t)NATOM*16; idx += (size_t)gridDim.x*256){
    int n = (int)(idx >> 4), c4 = (int)(idx & 15)*4;
    size_t off = (size_t)n*64 + c4;
    float4 mv = ld4(meanacc + off);
    float rc = PREMUL ? recip[n] : 1.0f;
    uint2 hh = *(const uint2*)(atom_h + off);
    uint2 ll = *(const uint2*)(atom_l + off);
    float m4[4] = {mv.x, mv.y, mv.z, mv.w};
    unsigned short hs[4] = {(unsigned short)(hh.x & 0xFFFF), (unsigned short)(hh.x >> 16),
                            (unsigned short)(hh.y & 0xFFFF), (unsigned short)(hh.y >> 16)};
    unsigned short ls[4] = {(unsigned short)(ll.x & 0xFFFF), (unsigned short)(ll.x >> 16),
                            (unsigned short)(ll.y & 0xFFFF), (unsigned short)(ll.y >> 16)};
    unsigned oh[4], ol[4];
    #pragma unroll
    for (int r = 0; r < 4; ++r){
      float prev = bfu(hs[r]) + bfu(ls[r]);
      float a = softplus_fast(prev + m4[r]*rc*scale[c4+r] + shift[c4+r]);
      unsigned short h, l;
      rne_split(a, h, l);
      oh[r] = h; ol[r] = l;
    }
    *(uint2*)(atom_h + off) = make_uint2(oh[0] | (oh[1] << 16), oh[2] | (oh[3] << 16));
    *(uint2*)(atom_l + off) = make_uint2(ol[0] | (ol[1] << 16), ol[2] | (ol[3] << 16));
  }
}

// ---------------------------------------------------------------- gate MLP, pass 1
__global__ __launch_bounds__(256, 2) void gate_pass1(const short* __restrict__ atom_h,
                                                     const short* __restrict__ atom_l,
                                                     const float* __restrict__ W1, const float* __restrict__ b1,
                                                     float* __restrict__ hbuf,
                                                     float* __restrict__ partial){
  __shared__ float As[256*65];   // 66.6 KB
  __shared__ float Wl[64*16];
  int t = threadIdx.x;
  *(float4*)&Wl[t*4] = ld4(W1 + t*4);
  const short* hsrc = atom_h + (size_t)blockIdx.x*256*64;
  const short* lsrc = atom_l + (size_t)blockIdx.x*256*64;
  #pragma unroll
  for (int j = 0; j < 8; j++){
    int idx = j*256 + t;
    uint4 hv = *(const uint4*)(hsrc + idx*8);
    uint4 lv = *(const uint4*)(lsrc + idx*8);
    int r = idx >> 3, c = (idx & 7)*8;
    float* d = &As[r*65 + c];
    unsigned hw[4] = {hv.x,hv.y,hv.z,hv.w}, lw[4] = {lv.x,lv.y,lv.z,lv.w};
    #pragma unroll
    for (int i = 0; i < 4; i++){
      d[2*i]   = __uint_as_float(hw[i] << 16)          + __uint_as_float(lw[i] << 16);
      d[2*i+1] = __uint_as_float(hw[i] & 0xFFFF0000u)  + __uint_as_float(lw[i] & 0xFFFF0000u);
    }
  }
  __syncthreads();
  float h[16];
  #pragma unroll
  for (int c=0;c<16;c++) h[c] = b1[c];
  const float* ar = &As[t*65];
  #pragma unroll 8
  for (int k=0;k<64;k++){
    float a = ar[k];
    #pragma unroll
    for (int c=0;c<16;c++) h[c] += a*Wl[k*16+c];
  }
  size_t n = (size_t)blockIdx.x*256 + t;
  #pragma unroll
  for (int c=0;c<16;c+=4)
    *(float4*)&hbuf[n*16+c] = make_float4(h[c],h[c+1],h[c+2],h[c+3]);
  __syncthreads();
  #pragma unroll
  for (int c=0;c<16;c++){
    float v = h[c], v2 = h[c]*h[c];
    for (int off=32; off; off>>=1){ v += __shfl_down(v,off); v2 += __shfl_down(v2,off); }
    if ((t&63)==0){ As[(t>>6)*32 + c] = v; As[(t>>6)*32 + 16 + c] = v2; }
  }
  __syncthreads();
  if (t < 32){
    float v = As[t] + As[32+t] + As[64+t] + As[96+t];
    int col = (t < 16) ? t : (128 + t - 16);
    partial[(size_t)blockIdx.x*256 + col] = v;
  }
}

// ---------------------------------------------------------------- gate MLP, pass 2
__global__ __launch_bounds__(256) void gate_pass2(const float* __restrict__ hbuf,
                                                  const float* __restrict__ scale, const float* __restrict__ shift,
                                                  const float* __restrict__ W2, const float* __restrict__ b2,
                                                  const int* __restrict__ cry,
                                                  float* __restrict__ gate, unsigned* __restrict__ gmaxk){
  int n = blockIdx.x*256 + threadIdx.x;
  float g = b2[0];
  #pragma unroll
  for (int c=0;c<16;c+=4){
    float4 hv = ld4(hbuf + (size_t)n*16 + c);
    float4 sc = ld4(scale + c), sh = ld4(shift + c), w = ld4(W2 + c);
    g += fmaxf(hv.x*sc.x+sh.x,0.f)*w.x + fmaxf(hv.y*sc.y+sh.y,0.f)*w.y
       + fmaxf(hv.z*sc.z+sh.z,0.f)*w.z + fmaxf(hv.w*sc.w+sh.w,0.f)*w.w;
  }
  gate[n] = g;
  atomicMax(&gmaxk[cry[n]], fkey(g));
}

__global__ __launch_bounds__(256) void gate_exp(float* __restrict__ gate,
                                                const float* __restrict__ aw,
                                                const int* __restrict__ cry,
                                                const unsigned* __restrict__ gmaxk,
                                                float* __restrict__ gsum){
  int n = blockIdx.x*256 + threadIdx.x;
  if (n < NATOM){
    int c = cry[n];
    float w = aw[n]*expf(gate[n] - fkeyinv(gmaxk[c]));
    gate[n] = w;
    atomicAdd(&gsum[c], w);
  }
}

// vectorized 4 cols/thread
__global__ __launch_bounds__(256) void crys_acc(const float* __restrict__ gate,
                                                const float* __restrict__ gsum,
                                                const int* __restrict__ cry,
                                                const short* __restrict__ atom_h,
                                                const short* __restrict__ atom_l,
                                                float* __restrict__ crys){
  for (size_t idx = (size_t)blockIdx.x*256 + threadIdx.x; idx < (size_t)NATOM*16; idx += (size_t)gridDim.x*256){
    int n = (int)(idx >> 4), j4 = (int)(idx & 15)*4;
    int c = cry[n];
    float wn = gate[n] / (gsum[c] + 1e-13f);
    size_t off = (size_t)n*64 + j4;
    uint2 hh = *(const uint2*)(atom_h + off);
    uint2 ll = *(const uint2*)(atom_l + off);
    unsigned short hs[4] = {(unsigned short)(hh.x & 0xFFFF), (unsigned short)(hh.x >> 16),
                            (unsigned short)(hh.y & 0xFFFF), (unsigned short)(hh.y >> 16)};
    unsigned short ls[4] = {(unsigned short)(ll.x & 0xFFFF), (unsigned short)(ll.x >> 16),
                            (unsigned short)(ll.y & 0xFFFF), (unsigned short)(ll.y >> 16)};
    float* dst = crys + (size_t)c*64 + j4;
    #pragma unroll
    for (int r = 0; r < 4; ++r)
      atomicAdd(dst + r, wn*(bfu(hs[r]) + bfu(ls[r])));
  }
}

// ---------------------------------------------------------------- fc head
__global__ __launch_bounds__(512) void fc_stats(const float* __restrict__ crys,
                                                const float* __restrict__ fcW, const float* __restrict__ fcb,
                                                float* __restrict__ hid,
                                                float* __restrict__ partial){
  __shared__ float Wl[64*128];
  __shared__ float cb[64][16];
  int t = threadIdx.x;
  for (int j = t; j < 64*32; j += 512)
    *(float4*)&Wl[j*4] = ld4(fcW + j*4);
  int cg = t & 31, cr = t >> 5;
  float4 bias = ld4(fcb + cg*4);
  float ssum[4] = {0,0,0,0}, ssq[4] = {0,0,0,0};
  for (int chunk = blockIdx.x; chunk < NCRY/16; chunk += gridDim.x){
    int c0 = chunk*16;
    __syncthreads();
    for (int j = t; j < 256; j += 512){
      int rr = j & 15, c = j >> 4;
      float4 v = ld4(crys + (size_t)(c0+rr)*64 + c*4);
      int k = c*4;
      cb[k][rr]=v.x; cb[k+1][rr]=v.y; cb[k+2][rr]=v.z; cb[k+3][rr]=v.w;
    }
    __syncthreads();
    float4 acc = bias;
    #pragma unroll 4
    for (int k=0;k<64;k++){
      float a = cb[k][cr];
      float4 w = *(float4*)&Wl[k*128 + cg*4];
      acc.x += a*w.x; acc.y += a*w.y; acc.z += a*w.z; acc.w += a*w.w;
    }
    *(float4*)&hid[(size_t)(c0+cr)*128 + cg*4] = acc;
    ssum[0]+=acc.x; ssum[1]+=acc.y; ssum[2]+=acc.z; ssum[3]+=acc.w;
    ssq[0]+=acc.x*acc.x; ssq[1]+=acc.y*acc.y; ssq[2]+=acc.z*acc.z; ssq[3]+=acc.w*acc.w;
  }
  __syncthreads();
  float* red = Wl;
  #pragma unroll
  for (int q=0;q<4;q++){ red[t*8+q] = ssum[q]; red[t*8+4+q] = ssq[q]; }
  __syncthreads();
  if (t < 128){
    int cgj = t >> 2, q = t & 3;
    float s = 0.f, sq = 0.f;
    for (int cri=0; cri<16; cri++){
      int tt = cri*32 + cgj;
      s  += red[tt*8+q];
      sq += red[tt*8+4+q];
    }
    partial[(size_t)blockIdx.x*256 + t]       = s;
    partial[(size_t)blockIdx.x*256 + 128 + t] = sq;
  }
}

__global__ __launch_bounds__(256) void out_kernel(const float* __restrict__ hid,
                                                  const float* __restrict__ scale, const float* __restrict__ shift,
                                                  const float* __restrict__ outW, const float* __restrict__ outb,
                                                  float* __restrict__ out){
  int c = blockIdx.x*4 + (threadIdx.x >> 6);
  int l = threadIdx.x & 63;
  float v = softplusf_(hid[(size_t)c*128 + l]*scale[l] + shift[l])*outW[l]
          + softplusf_(hid[(size_t)c*128 + 64 + l]*scale[64+l] + shift[64+l])*outW[64+l];
  for (int off=32; off; off >>= 1) v += __shfl_down(v, off);
  if (l == 0) out[c] = v + outb[0];
}

// ---------------------------------------------------------------- launch
extern "C" void kernel_launch(void* const* d_in, const int* in_sizes, int n_in,
                              void* d_out, int out_size, void* d_ws, size_t ws_size,
                              hipStream_t stream){
  const float* aw    = (const float*)d_in[0];
  const float* orig  = (const float*)d_in[1];
  const float* nbr   = (const float*)d_in[2];
  const int*   sidx  = (const int*)d_in[3];
  const int*   nidx  = (const int*)d_in[4];
  const int*   cry   = (const int*)d_in[5];
  const float* embW  = (const float*)d_in[6];
  const float* embB  = (const float*)d_in[7];
  const float* filtW = (const float*)d_in[8];
  const float* filtB = (const float*)d_in[9];
  const float* coreW = (const float*)d_in[10];
  const float* coreB = (const float*)d_in[11];
  const float* bnfg  = (const float*)d_in[12];
  const float* bnfb  = (const float*)d_in[13];
  const float* bncg  = (const float*)d_in[14];
  const float* bncb  = (const float*)d_in[15];
  const float* bnog  = (const float*)d_in[16];
  const float* bnob  = (const float*)d_in[17];
  const float* gW1   = (const float*)d_in[18];
  const float* gb1   = (const float*)d_in[19];
  const float* gbng  = (const float*)d_in[20];
  const float* gbnb  = (const float*)d_in[21];
  const float* gW2   = (const float*)d_in[22];
  const float* gb2   = (const float*)d_in[23];
  const float* fcW   = (const float*)d_in[24];
  const float* fcb   = (const float*)d_in[25];
  const float* fcbng = (const float*)d_in[26];
  const float* fcbnb = (const float*)d_in[27];
  const float* outW  = (const float*)d_in[28];
  const float* outb  = (const float*)d_in[29];
  float* out = (float*)d_out;

  float* ws      = (float*)d_ws;
  float* meanacc = ws;                              // N*64  (reused as hbuf)
  float* cnt     = meanacc + (size_t)NATOM*64;      // N (recip, fallback only)
  float* gate    = cnt     + NATOM;                 // N
  float* gmaxk   = gate    + NATOM;                 // C
  float* gsum    = gmaxk   + NCRY;                  // C (adjacent to gmaxk -> 1 memset)
  float* crys    = gsum    + NCRY;                  // C*64
  float* hid     = crys    + (size_t)NCRY*64;       // C*128
  float* part2   = hid     + (size_t)NCRY*128;      // 32*256
  float* scale   = part2   + 32*256;                // 128
  float* shift   = scale   + 128;                   // 128
  short* wth     = (short*)(shift + 128);           // 3*128*160
  short* wtl     = wth + 3*128*160;
  float* partial = (float*)(wtl + 3*128*160);       // 4096*256 floats (4 MB)
  short* atom_h  = (short*)(partial + 4096*256);    // N*64 shorts
  short* atom_l  = atom_h + (size_t)NATOM*64;       // N*64 shorts
  short* weh     = atom_l + (size_t)NATOM*64;       // 64*224 shorts
  short* wel     = weh + 64*224;                    // 64*224 shorts
  short* feap    = wel + 64*224;                    // M*32 shorts (permuted fea, bf16)
  int*   cnti    = (int*)(feap + (size_t)MEDGE*32); // N
  int*   ctr     = cnti + NATOM;                    // N (adjacent to cnti -> 1 memset)
  int*   loc     = ctr + NATOM;                     // N
  int*   base    = loc + NATOM;                     // N
  int*   bsum    = base + NATOM;                    // 1024
  int*   sidx_s  = bsum + 1024;                     // M
  int*   nidx_s  = sidx_s + MEDGE;                  // M
  unsigned short* ycache = (unsigned short*)(nidx_s + MEDGE);  // M*128 fp16 (268 MB, optional)
  size_t need = (size_t)((char*)(ycache + (size_t)MEDGE*128) - (char*)d_ws);
  bool use_yc = (ws_size >= need);
  unsigned short* yc = use_yc ? ycache : nullptr;
  (void)in_sizes; (void)n_in; (void)out_size;

  // prep: histogram + scan + sort-by-self + weight prep + embedding
  hipMemsetAsync(cnti, 0, 2*NATOM*sizeof(int), stream);   // cnti + ctr
  hist_kernel<<<2048, 256, 0, stream>>>(sidx, cnti);
  scan1<<<NATOM/256, 256, 0, stream>>>(cnti, loc, bsum);
  scan2<<<1, 256, 0, stream>>>(bsum);
  scan3<<<NATOM/256, 256, 0, stream>>>(loc, bsum, base);
  wprep<<<240, 256, 0, stream>>>(filtW, coreW, wth, wtl);
  wprep_embed<<<56, 256, 0, stream>>>(embW, weh, wel);
  rank_kernel<<<2048, 256, 0, stream>>>(sidx, nidx, base, ctr, nbr, sidx_s, nidx_s, feap);
  embed_mfma<<<NATOM/64, 256, 0, stream>>>(orig, weh, wel, embB, atom_h, atom_l);
  if (!use_yc) recip_int<<<NATOM/256, 256, 0, stream>>>(cnti, cnt);

  // message-passing layers (sorted edge order)
  for (int i = 0; i < 3; ++i){
    const short* wthL = wth + (size_t)i*128*160;
    const short* wtlL = wtl + (size_t)i*128*160;
    const float* bf = filtB + i*64;
    const float* bc = coreB + i*64;
    edge_mfma<0><<<4096, 256, 0, stream>>>(atom_h, atom_l, feap, sidx_s, nidx_s, wthL, wtlL, bf, bc,
                                           nullptr, nullptr, partial, nullptr, yc);
    colstage<<<CSB, 256, 0, stream>>>(partial, part2, 4096);
    bnfin2_kernel<<<1, 128, 0, stream>>>(1.0f/MEDGE, part2,
                                         bnfg+i*64, bnfb+i*64, bncg+i*64, bncb+i*64, scale, shift);
    if (use_yc){
      aggregate<<<NATOM/128, 256, 0, stream>>>(ycache, base, cnti, scale, shift, meanacc, partial);
      colstage<<<CSB, 256, 0, stream>>>(partial, part2, NATOM/128);
      bnfin_kernel<<<1, 64, 0, stream>>>(64, 1.0f/NATOM, part2, bnog+i*64, bnob+i*64, scale, shift);
      atom_update<0><<<2048, 256, 0, stream>>>(atom_h, atom_l, meanacc, cnt, scale, shift);
    } else {
      hipMemsetAsync(meanacc, 0, (size_t)NATOM*64*sizeof(float), stream);
      edge_mfma<1><<<4096, 256, 0, stream>>>(atom_h, atom_l, feap, sidx_s, nidx_s, wthL, wtlL, bf, bc,
                                             scale, shift, nullptr, meanacc, nullptr);
      meanbn_stats<<<2048, 256, 0, stream>>>(cnt, meanacc, partial);
      colstage<<<CSB, 256, 0, stream>>>(partial, part2, 2048);
      bnfin_kernel<<<1, 64, 0, stream>>>(64, 1.0f/NATOM, part2, bnog+i*64, bnob+i*64, scale, shift);
      atom_update<1><<<2048, 256, 0, stream>>>(atom_h, atom_l, meanacc, cnt, scale, shift);
    }
  }

  // gate MLP + BN + attention pooling (hbuf reuses meanacc)
  float* hbuf = meanacc;
  gate_pass1<<<NATOM/256, 256, 0, stream>>>(atom_h, atom_l, gW1, gb1, hbuf, partial);
  colstage<<<CSB, 256, 0, stream>>>(partial, part2, NATOM/256);
  bnfin_kernel<<<1, 16, 0, stream>>>(16, 1.0f/NATOM, part2, gbng, gbnb, scale, shift);
  hipMemsetAsync(gmaxk, 0, 2*NCRY*sizeof(float), stream);   // gmaxk + gsum
  gate_pass2<<<NATOM/256, 256, 0, stream>>>(hbuf, scale, shift, gW2, gb2, cry, gate, (unsigned*)gmaxk);
  gate_exp<<<NATOM/256, 256, 0, stream>>>(gate, aw, cry, (const unsigned*)gmaxk, gsum);
  hipMemsetAsync(crys, 0, (size_t)NCRY*64*sizeof(float), stream);
  crys_acc<<<2048, 256, 0, stream>>>(gate, gsum, cry, atom_h, atom_l, crys);

  // fc head
  fc_stats<<<1024, 512, 0, stream>>>(crys, fcW, fcb, hid, partial);
  colstage<<<CSB, 256, 0, stream>>>(partial, part2, 1024);
  bnfin_kernel<<<1, 128, 0, stream>>>(128, 1.0f/NCRY, part2, fcbng, fcbnb, scale, shift);
  out_kernel<<<NCRY/4, 256, 0, stream>>>(hid, scale, shift, outW, outb, out);
}

// Round 20
// 1406.017 us; speedup vs baseline: 1.1567x; 1.1567x over previous
//
#include <hip/hip_runtime.h>
#include <hip/hip_fp16.h>
#include <cstdint>
#include <cstddef>

// Problem constants (from reference)
#define NATOM 262144
#define MEDGE 1048576
#define NCRY  32768
// ORIG=200, AF=64, NF=32, GH=16, H=128, NG=3

typedef __attribute__((ext_vector_type(8))) short short8v;   // 8 bf16 (4 VGPR)
typedef __attribute__((ext_vector_type(4))) float f32x4;     // MFMA acc

__device__ __forceinline__ float4 ld4(const float* p){ return *reinterpret_cast<const float4*>(p); }

__device__ __forceinline__ float softplusf_(float x){
  return fmaxf(x, 0.0f) + log1pf(expf(-fabsf(x)));
}
__device__ __forceinline__ float softplus_fast(float x){
  return fmaxf(x, 0.0f) + __logf(1.0f + __expf(-fabsf(x)));
}
__device__ __forceinline__ float sigmoid_fast(float y){
  return __builtin_amdgcn_rcpf(1.0f + __expf(-y));
}

__device__ __forceinline__ unsigned short rne_bf16(float f){
  unsigned u = __float_as_uint(f);
  unsigned r = u + 0x7FFFu + ((u >> 16) & 1u);
  return (unsigned short)(r >> 16);
}
__device__ __forceinline__ float bfu(unsigned short s){
  return __uint_as_float(((unsigned)s) << 16);
}

// monotonic float<->uint key for atomicMax-based segment max
__device__ __forceinline__ unsigned fkey(float x){
  unsigned b = __float_as_uint(x);
  return (b & 0x80000000u) ? ~b : (b | 0x80000000u);
}
__device__ __forceinline__ float fkeyinv(unsigned k){
  unsigned b = (k & 0x80000000u) ? (k & 0x7fffffffu) : ~k;
  return __uint_as_float(b);
}

// async global->LDS 16B copy (dest: wave-uniform base + lane*16 implicit)
__device__ __forceinline__ void gll16(const void* g, void* l){
  __builtin_amdgcn_global_load_lds((const __attribute__((address_space(1))) unsigned*)g,
                                   (__attribute__((address_space(3))) unsigned*)l, 16, 0, 0);
}

// RNE hi/lo split: a ~= bfu(h) + bfu(l)
__device__ __forceinline__ void rne_split(float a, unsigned short& h, unsigned short& l){
  h = rne_bf16(a);
  l = rne_bf16(a - bfu(h));
}

// ---------------------------------------------------------------- stats staging
#define CSB 32
__global__ __launch_bounds__(256) void colstage(const float* __restrict__ part,
                                                float* __restrict__ part2, int nb){
  int t = threadIdx.x;
  int rpb = nb / CSB;
  const float* p = part + (size_t)blockIdx.x*rpb*256 + t;
  float s = 0.f;
  #pragma unroll 4
  for (int r = 0; r < rpb; ++r) s += p[(size_t)r*256];
  part2[blockIdx.x*256 + t] = s;
}

// ---------------------------------------------------------------- edge sort by self atom (counting sort)
__global__ __launch_bounds__(256) void hist_kernel(const int* __restrict__ sidx, int* __restrict__ cnti){
  for (int m = blockIdx.x*256 + threadIdx.x; m < MEDGE; m += gridDim.x*256)
    atomicAdd(&cnti[sidx[m]], 1);
}

__global__ __launch_bounds__(256) void scan1(const int* __restrict__ cnti,
                                             int* __restrict__ loc, int* __restrict__ bsum){
  __shared__ int sm[256];
  int t = threadIdx.x;
  int v = cnti[blockIdx.x*256 + t];
  sm[t] = v;
  __syncthreads();
  for (int off = 1; off < 256; off <<= 1){
    int x = (t >= off) ? sm[t-off] : 0;
    __syncthreads();
    sm[t] += x;
    __syncthreads();
  }
  loc[blockIdx.x*256 + t] = sm[t] - v;     // exclusive
  if (t == 255) bsum[blockIdx.x] = sm[255];
}

__global__ __launch_bounds__(256) void scan2(int* __restrict__ bsum){
  __shared__ int sm[256];
  int t = threadIdx.x;
  int v0 = bsum[t*4+0], v1 = bsum[t*4+1], v2 = bsum[t*4+2], v3 = bsum[t*4+3];
  int tot = v0+v1+v2+v3;
  sm[t] = tot;
  __syncthreads();
  for (int off = 1; off < 256; off <<= 1){
    int x = (t >= off) ? sm[t-off] : 0;
    __syncthreads();
    sm[t] += x;
    __syncthreads();
  }
  int te = sm[t] - tot;
  bsum[t*4+0] = te;
  bsum[t*4+1] = te + v0;
  bsum[t*4+2] = te + v0 + v1;
  bsum[t*4+3] = te + v0 + v1 + v2;
}

__global__ __launch_bounds__(256) void scan3(const int* __restrict__ loc, const int* __restrict__ bsum,
                                             int* __restrict__ base){
  int i = blockIdx.x*256 + threadIdx.x;
  base[i] = loc[i] + bsum[i >> 8];
}

__global__ __launch_bounds__(256) void recip_int(const int* __restrict__ cnti, float* __restrict__ recip){
  int n = blockIdx.x*256 + threadIdx.x;
  if (n < NATOM) recip[n] = 1.0f / fmaxf((float)cnti[n], 1.0f);
}

// rank & permute: sidx_s/nidx_s sorted by self atom; nbr fea converted bf16 + permuted
__global__ __launch_bounds__(256) void rank_kernel(const int* __restrict__ sidx, const int* __restrict__ nidx,
                                                   const int* __restrict__ base, int* __restrict__ ctr,
                                                   const float* __restrict__ nbr,
                                                   int* __restrict__ sidx_s, int* __restrict__ nidx_s,
                                                   short* __restrict__ feap){
  for (int m = blockIdx.x*256 + threadIdx.x; m < MEDGE; m += gridDim.x*256){
    int s = sidx[m];
    int p = base[s] + atomicAdd(&ctr[s], 1);
    sidx_s[p] = s;
    nidx_s[p] = nidx[m];
    const float* src = nbr + (size_t)m*32;
    uint4* dst = (uint4*)(feap + (size_t)p*32);
    #pragma unroll
    for (int c = 0; c < 4; ++c){
      float4 a = ld4(src + c*8), b = ld4(src + c*8 + 4);
      float fv[8] = {a.x,a.y,a.z,a.w,b.x,b.y,b.z,b.w};
      unsigned w[4];
      #pragma unroll
      for (int i=0;i<4;i++)
        w[i] = (unsigned)rne_bf16(fv[2*i]) | ((unsigned)rne_bf16(fv[2*i+1]) << 16);
      dst[c] = make_uint4(w[0],w[1],w[2],w[3]);
    }
  }
}

// ---------------------------------------------------------------- embed W prep
__global__ __launch_bounds__(256) void wprep_embed(const float* __restrict__ embW,
                                                   short* __restrict__ Weh, short* __restrict__ Wel){
  int idx = blockIdx.x*256 + threadIdx.x;   // 64*224 = 14336
  if (idx >= 64*224) return;
  int k = idx % 224, c = idx / 224;
  float w = (k < 200) ? embW[(size_t)k*64 + c] : 0.0f;
  unsigned short h, l;
  rne_split(w, h, l);
  Weh[idx] = (short)h;
  Wel[idx] = (short)l;
}

// ---------------------------------------------------------------- embedding via split-bf16 MFMA
__global__ __launch_bounds__(256) void embed_mfma(const float* __restrict__ orig,
                                                  const short* __restrict__ Weh,
                                                  const short* __restrict__ Wel,
                                                  const float* __restrict__ bias,
                                                  short* __restrict__ atom_h,
                                                  short* __restrict__ atom_l){
  __shared__ uint4 ab4[3208];   // 51328 B
  char* ab = (char*)ab4;
  int t = threadIdx.x, lane = t & 63, wid = t >> 6;
  int r16 = lane & 15, g = lane >> 4;
  int col = wid*16 + r16;

  short8v Bh[7], Bl[7];
  #pragma unroll
  for (int ks = 0; ks < 7; ks++){
    int o = col*224 + ks*32 + g*8;
    Bh[ks] = *(const short8v*)(Weh + o);
    Bl[ks] = *(const short8v*)(Wel + o);
  }
  float bv = bias[col];
  int n0 = blockIdx.x * 64;
  const char* src = (const char*)orig + (size_t)n0*800;
  #pragma unroll
  for (int i = 0; i < 13; i++){
    int j = wid + i*4;
    if (j < 50) gll16(src + j*1024 + lane*16, ab + j*1024);
  }
  __syncthreads();

  #pragma unroll
  for (int grp = 0; grp < 4; grp++){
    f32x4 acc = {bv, bv, bv, bv};
    const char* arow = ab + (grp*16 + r16)*800;
    #pragma unroll
    for (int ks = 0; ks < 7; ks++){
      short8v ah, al;
      if (ks < 6 || g == 0){
        const float* f = (const float*)(arow + ks*128 + g*32);
        float4 f0 = *(const float4*)f, f1 = *(const float4*)(f+4);
        float fv[8] = {f0.x,f0.y,f0.z,f0.w,f1.x,f1.y,f1.z,f1.w};
        unsigned hw[4], lw[4];
        #pragma unroll
        for (int p = 0; p < 4; p++){
          unsigned short h0, l0, h1, l1;
          rne_split(fv[2*p], h0, l0);
          rne_split(fv[2*p+1], h1, l1);
          hw[p] = (unsigned)h0 | ((unsigned)h1 << 16);
          lw[p] = (unsigned)l0 | ((unsigned)l1 << 16);
        }
        ah = __builtin_bit_cast(short8v, make_uint4(hw[0],hw[1],hw[2],hw[3]));
        al = __builtin_bit_cast(short8v, make_uint4(lw[0],lw[1],lw[2],lw[3]));
      } else {
        ah = (short8v)0; al = (short8v)0;
      }
      acc = __builtin_amdgcn_mfma_f32_16x16x32_bf16(ah, Bh[ks], acc, 0, 0, 0);
      acc = __builtin_amdgcn_mfma_f32_16x16x32_bf16(al, Bh[ks], acc, 0, 0, 0);
      acc = __builtin_amdgcn_mfma_f32_16x16x32_bf16(ah, Bl[ks], acc, 0, 0, 0);
    }
    int rowb = n0 + grp*16 + g*4;
    #pragma unroll
    for (int r = 0; r < 4; r++){
      float a = acc[r];
      unsigned short h, l;
      rne_split(a, h, l);
      size_t off = (size_t)(rowb + r)*64 + col;
      atom_h[off] = (short)h;
      atom_l[off] = (short)l;
    }
  }
}

// ---------------------------------------------------------------- W prep (edge)
__global__ __launch_bounds__(256) void wprep(const float* __restrict__ filtW, const float* __restrict__ coreW,
                                             short* __restrict__ Wth, short* __restrict__ Wtl){
  int idx = blockIdx.x*256 + threadIdx.x;   // 3*128*160 = 61440
  if (idx >= 3*128*160) return;
  int k = idx % 160; int rest = idx / 160; int c = rest & 127; int layer = rest >> 7;
  float w = (c < 64) ? filtW[((size_t)layer*160 + k)*64 + c] : coreW[((size_t)layer*160 + k)*64 + (c-64)];
  unsigned short h, l;
  rne_split(w, h, l);
  Wth[idx] = (short)h;
  Wtl[idx] = (short)l;
}

// ---------------------------------------------------------------- edge GEMM: 2-phase gll pipeline, TILE=32
// LDS: 28 cols x 32 edges x 16B = 14KB/buffer (28KB total -> 5 blocks/CU).
// cols: 0-7 self_h, 8-15 nbr_h, 16-19 fea, 20-27 self_l  (nbr lo + fea lo dropped, RNE-unbiased).
// PASS0 optionally writes ycache fp16: unit8B idx = (e>>2)*128 + col, elem (e&3).
#define NT_PER_BLK 8

#define MFMA_B(A,B,ACC) ACC = __builtin_amdgcn_mfma_f32_16x16x32_bf16(A, B, ACC, 0, 0, 0)

template<int PASS>
__global__ __launch_bounds__(256) void edge_mfma(
    const short* __restrict__ atom_h, const short* __restrict__ atom_l,
    const short* __restrict__ nbr_h,
    const int* __restrict__ sidx, const int* __restrict__ nidx,
    const short* __restrict__ Wth, const short* __restrict__ Wtl,
    const float* __restrict__ bfp, const float* __restrict__ bcp,
    const float* __restrict__ scale, const float* __restrict__ shift,
    float* __restrict__ partial,
    float* __restrict__ meanacc,
    unsigned short* __restrict__ ycache)
{
  __shared__ uint4 xb[2][28*32];   // 2 x 14 KB
  int t = threadIdx.x, lane = t & 63, wid = t >> 6;   // 4 waves
  int r16 = lane & 15, g = lane >> 4;
  int colf = wid*16 + r16, colc = colf + 64;
  int el = lane & 31;

  short8v Bhf[5], Blf[5], Bhc[5], Blc[5];
  {
    const short* wfh = Wth + colf*160;
    const short* wch = Wth + colc*160;
    const short* wfl = Wtl + colf*160;
    const short* wcl = Wtl + colc*160;
    #pragma unroll
    for (int ks = 0; ks < 5; ks++){
      int o = ks*32 + g*8;
      Bhf[ks] = *(const short8v*)(wfh + o);
      Bhc[ks] = *(const short8v*)(wch + o);
      Blf[ks] = *(const short8v*)(wfl + o);
      Blc[ks] = *(const short8v*)(wcl + o);
    }
  }
  float bfv = bfp[colf], bcv = bcp[colf];
  float sf = 0.f, hf = 0.f, sc = 0.f, hc = 0.f;
  if (PASS == 1){ sf = scale[colf]; hf = shift[colf]; sc = scale[colc]; hc = shift[colc]; }
  float s0 = 0.f, q0 = 0.f, s1 = 0.f, q1 = 0.f;

  int tile0 = blockIdx.x * NT_PER_BLK;

  #define STAGE(BUF, TILE, SE, NE)                                              \
  {                                                                             \
    uint4* dst = (uint4*)(BUF);                                                 \
    int e0s_ = (TILE)*32;                                                       \
    _Pragma("unroll")                                                           \
    for (int j = wid; j < 14; j += 4){                                          \
      int c = 2*j + (lane >> 5);                                                \
      const short* src;                                                         \
      if      (c < 8)  src = atom_h + (size_t)(SE)*64 + c*8;                    \
      else if (c < 16) src = atom_h + (size_t)(NE)*64 + (c-8)*8;                \
      else if (c < 20) src = nbr_h + (size_t)(e0s_+el)*32 + (c-16)*8;           \
      else             src = atom_l + (size_t)(SE)*64 + (c-20)*8;               \
      gll16(src, dst + j*64);                                                   \
    }                                                                           \
  }

  int se, ne;
  { int e = tile0*32 + el; se = sidx[e]; ne = nidx[e]; }
  STAGE(xb[0], tile0, se, ne);
  { int e = (tile0+1)*32 + el; se = sidx[e]; ne = nidx[e]; }

  for (int tt = 0; tt < NT_PER_BLK; ++tt){
    asm volatile("s_waitcnt vmcnt(0)" ::: "memory");
    __builtin_amdgcn_s_barrier();           // LDS tile tt ready for all waves
    if (tt+1 < NT_PER_BLK){
      STAGE(xb[(tt+1)&1], tile0+tt+1, se, ne);
      if (tt+2 < NT_PER_BLK){ int e = (tile0+tt+2)*32 + el; se = sidx[e]; ne = nidx[e]; }
    }
    int e0 = (tile0+tt)*32;
    const char* buf = (const char*)xb[tt & 1];
    #pragma unroll
    for (int grp = 0; grp < 2; ++grp){
      f32x4 accf = {bfv,bfv,bfv,bfv}, accc = {bcv,bcv,bcv,bcv};
      const char* base = buf + (grp*16 + r16)*16;
      #pragma unroll
      for (int ks = 0; ks < 5; ++ks){
        short8v ah = *(const short8v*)(base + (ks*4+g)*512);
        MFMA_B(ah, Bhf[ks], accf); MFMA_B(ah, Bhc[ks], accc);
        MFMA_B(ah, Blf[ks], accf); MFMA_B(ah, Blc[ks], accc);
        if (ks < 2){
          short8v al = *(const short8v*)(base + (20+ks*4+g)*512);
          MFMA_B(al, Bhf[ks], accf); MFMA_B(al, Bhc[ks], accc);
        }
      }
      if (PASS == 0){
        #pragma unroll
        for (int r = 0; r < 4; r++){
          float yf = accf[r], yc = accc[r];
          s0 += yf; q0 += yf*yf; s1 += yc; q1 += yc*yc;
        }
        if (ycache){
          int ebase = e0 + grp*16 + g*4;         // 4 consecutive edges, 4-aligned
          uint2 pf, pc;
          #pragma unroll
          for (int r = 0; r < 4; r++){
            ((__half*)&pf)[r] = __float2half_rn(accf[r]);
            ((__half*)&pc)[r] = __float2half_rn(accc[r]);
          }
          uint2* yrow = (uint2*)ycache + (size_t)(ebase >> 2)*128;
          yrow[colf]      = pf;
          yrow[64 + colf] = pc;
        }
      } else {
        // sorted edges: run-compress atomics (thread's 4 edges are consecutive)
        int ebase = e0 + grp*16 + g*4;
        int a_prev = sidx[ebase];
        float accum = 0.f;
        #pragma unroll
        for (int r = 0; r < 4; r++){
          float f  = sigmoid_fast(accf[r]*sf + hf);
          float c2 = softplus_fast(accc[r]*sc + hc);
          int a = sidx[ebase + r];
          if (a != a_prev){
            atomicAdd(&meanacc[(size_t)a_prev*64 + colf], accum);
            accum = 0.f;
            a_prev = a;
          }
          accum += f*c2;
        }
        atomicAdd(&meanacc[(size_t)a_prev*64 + colf], accum);
      }
    }
  }
  #undef STAGE

  if (PASS == 0){
    s0 += __shfl_xor(s0,16); s0 += __shfl_xor(s0,32);
    q0 += __shfl_xor(q0,16); q0 += __shfl_xor(q0,32);
    s1 += __shfl_xor(s1,16); s1 += __shfl_xor(s1,32);
    q1 += __shfl_xor(q1,16); q1 += __shfl_xor(q1,32);
    __syncthreads();
    float* scm = (float*)&xb[0][0];
    if (g == 0)
      *(float4*)&scm[(wid*16 + r16)*4] = make_float4(s0, q0, s1, q1);
    __syncthreads();
    {
      int stat = t >> 7, colx = t & 127;
      int isc = (colx >= 64) ? 1 : 0;
      int cc = colx & 63;
      int v = isc*2 + stat;
      partial[(size_t)blockIdx.x*256 + stat*128 + colx] = scm[((cc>>4)*16 + (cc&15))*4 + v];
    }
  }
}

// ---------------------------------------------------------------- fused segment-mean + BN-o stats from ycache
__global__ __launch_bounds__(256) void aggregate(const unsigned short* __restrict__ ycache,
                                                 const int* __restrict__ base,
                                                 const int* __restrict__ cnti,
                                                 const float* __restrict__ scale,
                                                 const float* __restrict__ shift,
                                                 float* __restrict__ meanacc,
                                                 float* __restrict__ partial){
  int t = threadIdx.x, j = t & 63, w = t >> 6;
  float sf = scale[j], hf = shift[j];
  float sc = scale[j+64], hc = shift[j+64];
  float s = 0.f, q = 0.f;
  int n0 = blockIdx.x*128 + w*32;        // grid 2048 -> 128 atoms/block, 32/wave
  for (int i = 0; i < 32; ++i){
    int n = n0 + i;
    int b0 = base[n], deg = cnti[n];
    float acc = 0.f;
    if (deg > 0){
      int q0 = b0 >> 2, q1 = (b0 + deg + 3) >> 2;
      for (int qq = q0; qq < q1; ++qq){
        const uint2* yrow = (const uint2*)ycache + (size_t)qq*128;
        uint2 f4 = yrow[j], c4 = yrow[64 + j];
        int e0 = qq*4;
        #pragma unroll
        for (int r = 0; r < 4; ++r){
          int e = e0 + r;
          if (e >= b0 && e < b0 + deg){
            float yf = __half2float(((const __half*)&f4)[r]);
            float yc = __half2float(((const __half*)&c4)[r]);
            acc += sigmoid_fast(yf*sf + hf) * softplus_fast(yc*sc + hc);
          }
        }
      }
    }
    float mean = acc / fmaxf((float)deg, 1.0f);
    meanacc[(size_t)n*64 + j] = mean;
    s += mean; q += mean*mean;
  }
  __shared__ float red[4][128];
  red[w][j] = s; red[w][64+j] = q;
  __syncthreads();
  if (t < 64){
    partial[(size_t)blockIdx.x*256 + t]       = red[0][t]+red[1][t]+red[2][t]+red[3][t];
    partial[(size_t)blockIdx.x*256 + 128 + t] = red[0][64+t]+red[1][64+t]+red[2][64+t]+red[3][64+t];
  }
}

// ---------------------------------------------------------------- BN finalize (reads part2)
__global__ void bnfin_kernel(int nf, float invcnt, const float* __restrict__ p2,
                             const float* __restrict__ g, const float* __restrict__ b,
                             float* __restrict__ scale, float* __restrict__ shift){
  int j = threadIdx.x;
  if (j >= nf) return;
  float s = 0.f, q = 0.f;
  #pragma unroll 4
  for (int r = 0; r < CSB; ++r){
    s += p2[r*256 + j];
    q += p2[r*256 + 128 + j];
  }
  float m = s*invcnt;
  float v = fmaxf(q*invcnt - m*m, 0.0f);
  float is = rsqrtf(v + 1e-5f);
  float sc = g[j]*is;
  scale[j] = sc;
  shift[j] = b[j] - m*sc;
}

__global__ void bnfin2_kernel(float invcnt, const float* __restrict__ p2,
                              const float* __restrict__ g0, const float* __restrict__ b0,
                              const float* __restrict__ g1, const float* __restrict__ b1,
                              float* __restrict__ scale, float* __restrict__ shift){
  int j = threadIdx.x;   // 128
  float s = 0.f, q = 0.f;
  #pragma unroll 4
  for (int r = 0; r < CSB; ++r){
    s += p2[r*256 + j];
    q += p2[r*256 + 128 + j];
  }
  float m = s*invcnt;
  float v = fmaxf(q*invcnt - m*m, 0.0f);
  float is = rsqrtf(v + 1e-5f);
  float gg = (j < 64) ? g0[j] : g1[j-64];
  float bb = (j < 64) ? b0[j] : b1[j-64];
  float sc = gg*is;
  scale[j] = sc;
  shift[j] = bb - m*sc;
}

// ---------------------------------------------------------------- stats of mean = meanacc * recip (fallback path)
__global__ __launch_bounds__(256) void meanbn_stats(const float* __restrict__ recip,
                                                    const float* __restrict__ meanacc,
                                                    float* __restrict__ partial){
  int t = threadIdx.x;
  float s = 0.f, q = 0.f;
  for (size_t idx = (size_t)blockIdx.x*256 + t; idx < (size_t)NATOM*64; idx += (size_t)gridDim.x*256){
    int n = (int)(idx >> 6);
    float v = meanacc[idx]*recip[n];
    s += v; q += v*v;
  }
  __shared__ float red[256][2];
  red[t][0]=s; red[t][1]=q;
  __syncthreads();
  if (t < 64){
    for (int i=1;i<4;i++){ s += red[t+64*i][0]; q += red[t+64*i][1]; }
    partial[(size_t)blockIdx.x*256 + t]       = s;
    partial[(size_t)blockIdx.x*256 + 128 + t] = q;
  }
}

// atom = softplus(atom + mean*scale + shift), vectorized 4 cols/thread
template<int PREMUL>
__global__ __launch_bounds__(256) void atom_update(short* __restrict__ atom_h,
                                                   short* __restrict__ atom_l,
                                                   const float* __restrict__ meanacc,
                                                   const float* __restrict__ recip,
                                                   const float* __restrict__ scale,
                                                   const float* __restrict__ shift){
  for (size_t idx = (size_t)blockIdx.x*256 + threadIdx.x; idx < (size_t)NATOM*16; idx += (size_t)gridDim.x*256){
    int n = (int)(idx >> 4), c4 = (int)(idx & 15)*4;
    size_t off = (size_t)n*64 + c4;
    float4 mv = ld4(meanacc + off);
    float rc = PREMUL ? recip[n] : 1.0f;
    uint2 hh = *(const uint2*)(atom_h + off);
    uint2 ll = *(const uint2*)(atom_l + off);
    float m4[4] = {mv.x, mv.y, mv.z, mv.w};
    unsigned short hs[4] = {(unsigned short)(hh.x & 0xFFFF), (unsigned short)(hh.x >> 16),
                            (unsigned short)(hh.y & 0xFFFF), (unsigned short)(hh.y >> 16)};
    unsigned short ls[4] = {(unsigned short)(ll.x & 0xFFFF), (unsigned short)(ll.x >> 16),
                            (unsigned short)(ll.y & 0xFFFF), (unsigned short)(ll.y >> 16)};
    unsigned oh[4], ol[4];
    #pragma unroll
    for (int r = 0; r < 4; ++r){
      float prev = bfu(hs[r]) + bfu(ls[r]);
      float a = softplus_fast(prev + m4[r]*rc*scale[c4+r] + shift[c4+r]);
      unsigned short h, l;
      rne_split(a, h, l);
      oh[r] = h; ol[r] = l;
    }
    *(uint2*)(atom_h + off) = make_uint2(oh[0] | (oh[1] << 16), oh[2] | (oh[3] << 16));
    *(uint2*)(atom_l + off) = make_uint2(ol[0] | (ol[1] << 16), ol[2] | (ol[3] << 16));
  }
}

// ---------------------------------------------------------------- gate MLP, pass 1
__global__ __launch_bounds__(256, 2) void gate_pass1(const short* __restrict__ atom_h,
                                                     const short* __restrict__ atom_l,
                                                     const float* __restrict__ W1, const float* __restrict__ b1,
                                                     float* __restrict__ hbuf,
                                                     float* __restrict__ partial){
  __shared__ float As[256*65];   // 66.6 KB
  __shared__ float Wl[64*16];
  int t = threadIdx.x;
  *(float4*)&Wl[t*4] = ld4(W1 + t*4);
  const short* hsrc = atom_h + (size_t)blockIdx.x*256*64;
  const short* lsrc = atom_l + (size_t)blockIdx.x*256*64;
  #pragma unroll
  for (int j = 0; j < 8; j++){
    int idx = j*256 + t;
    uint4 hv = *(const uint4*)(hsrc + idx*8);
    uint4 lv = *(const uint4*)(lsrc + idx*8);
    int r = idx >> 3, c = (idx & 7)*8;
    float* d = &As[r*65 + c];
    unsigned hw[4] = {hv.x,hv.y,hv.z,hv.w}, lw[4] = {lv.x,lv.y,lv.z,lv.w};
    #pragma unroll
    for (int i = 0; i < 4; i++){
      d[2*i]   = __uint_as_float(hw[i] << 16)          + __uint_as_float(lw[i] << 16);
      d[2*i+1] = __uint_as_float(hw[i] & 0xFFFF0000u)  + __uint_as_float(lw[i] & 0xFFFF0000u);
    }
  }
  __syncthreads();
  float h[16];
  #pragma unroll
  for (int c=0;c<16;c++) h[c] = b1[c];
  const float* ar = &As[t*65];
  #pragma unroll 8
  for (int k=0;k<64;k++){
    float a = ar[k];
    #pragma unroll
    for (int c=0;c<16;c++) h[c] += a*Wl[k*16+c];
  }
  size_t n = (size_t)blockIdx.x*256 + t;
  #pragma unroll
  for (int c=0;c<16;c+=4)
    *(float4*)&hbuf[n*16+c] = make_float4(h[c],h[c+1],h[c+2],h[c+3]);
  __syncthreads();
  #pragma unroll
  for (int c=0;c<16;c++){
    float v = h[c], v2 = h[c]*h[c];
    for (int off=32; off; off>>=1){ v += __shfl_down(v,off); v2 += __shfl_down(v2,off); }
    if ((t&63)==0){ As[(t>>6)*32 + c] = v; As[(t>>6)*32 + 16 + c] = v2; }
  }
  __syncthreads();
  if (t < 32){
    float v = As[t] + As[32+t] + As[64+t] + As[96+t];
    int col = (t < 16) ? t : (128 + t - 16);
    partial[(size_t)blockIdx.x*256 + col] = v;
  }
}

// ---------------------------------------------------------------- gate MLP, pass 2
__global__ __launch_bounds__(256) void gate_pass2(const float* __restrict__ hbuf,
                                                  const float* __restrict__ scale, const float* __restrict__ shift,
                                                  const float* __restrict__ W2, const float* __restrict__ b2,
                                                  const int* __restrict__ cry,
                                                  float* __restrict__ gate, unsigned* __restrict__ gmaxk){
  int n = blockIdx.x*256 + threadIdx.x;
  float g = b2[0];
  #pragma unroll
  for (int c=0;c<16;c+=4){
    float4 hv = ld4(hbuf + (size_t)n*16 + c);
    float4 sc = ld4(scale + c), sh = ld4(shift + c), w = ld4(W2 + c);
    g += fmaxf(hv.x*sc.x+sh.x,0.f)*w.x + fmaxf(hv.y*sc.y+sh.y,0.f)*w.y
       + fmaxf(hv.z*sc.z+sh.z,0.f)*w.z + fmaxf(hv.w*sc.w+sh.w,0.f)*w.w;
  }
  gate[n] = g;
  atomicMax(&gmaxk[cry[n]], fkey(g));
}

__global__ __launch_bounds__(256) void gate_exp(float* __restrict__ gate,
                                                const float* __restrict__ aw,
                                                const int* __restrict__ cry,
                                                const unsigned* __restrict__ gmaxk,
                                                float* __restrict__ gsum){
  int n = blockIdx.x*256 + threadIdx.x;
  if (n < NATOM){
    int c = cry[n];
    float w = aw[n]*expf(gate[n] - fkeyinv(gmaxk[c]));
    gate[n] = w;
    atomicAdd(&gsum[c], w);
  }
}

// per-column: wave = one atom's 64 cols (distinct addresses, no same-address conflicts)
__global__ __launch_bounds__(256) void crys_acc(const float* __restrict__ gate,
                                                const float* __restrict__ gsum,
                                                const int* __restrict__ cry,
                                                const short* __restrict__ atom_h,
                                                const short* __restrict__ atom_l,
                                                float* __restrict__ crys){
  for (size_t idx = (size_t)blockIdx.x*256 + threadIdx.x; idx < (size_t)NATOM*64; idx += (size_t)gridDim.x*256){
    int n = (int)(idx >> 6), j = (int)(idx & 63);
    int c = cry[n];
    float wn = gate[n] / (gsum[c] + 1e-13f);
    float a = bfu((unsigned short)atom_h[idx]) + bfu((unsigned short)atom_l[idx]);
    atomicAdd(&crys[(size_t)c*64 + j], wn*a);
  }
}

// ---------------------------------------------------------------- fc head
__global__ __launch_bounds__(512) void fc_stats(const float* __restrict__ crys,
                                                const float* __restrict__ fcW, const float* __restrict__ fcb,
                                                float* __restrict__ hid,
                                                float* __restrict__ partial){
  __shared__ float Wl[64*128];
  __shared__ float cb[64][16];
  int t = threadIdx.x;
  for (int j = t; j < 64*32; j += 512)
    *(float4*)&Wl[j*4] = ld4(fcW + j*4);
  int cg = t & 31, cr = t >> 5;
  float4 bias = ld4(fcb + cg*4);
  float ssum[4] = {0,0,0,0}, ssq[4] = {0,0,0,0};
  for (int chunk = blockIdx.x; chunk < NCRY/16; chunk += gridDim.x){
    int c0 = chunk*16;
    __syncthreads();
    for (int j = t; j < 256; j += 512){
      int rr = j & 15, c = j >> 4;
      float4 v = ld4(crys + (size_t)(c0+rr)*64 + c*4);
      int k = c*4;
      cb[k][rr]=v.x; cb[k+1][rr]=v.y; cb[k+2][rr]=v.z; cb[k+3][rr]=v.w;
    }
    __syncthreads();
    float4 acc = bias;
    #pragma unroll 4
    for (int k=0;k<64;k++){
      float a = cb[k][cr];
      float4 w = *(float4*)&Wl[k*128 + cg*4];
      acc.x += a*w.x; acc.y += a*w.y; acc.z += a*w.z; acc.w += a*w.w;
    }
    *(float4*)&hid[(size_t)(c0+cr)*128 + cg*4] = acc;
    ssum[0]+=acc.x; ssum[1]+=acc.y; ssum[2]+=acc.z; ssum[3]+=acc.w;
    ssq[0]+=acc.x*acc.x; ssq[1]+=acc.y*acc.y; ssq[2]+=acc.z*acc.z; ssq[3]+=acc.w*acc.w;
  }
  __syncthreads();
  float* red = Wl;
  #pragma unroll
  for (int q=0;q<4;q++){ red[t*8+q] = ssum[q]; red[t*8+4+q] = ssq[q]; }
  __syncthreads();
  if (t < 128){
    int cgj = t >> 2, q = t & 3;
    float s = 0.f, sq = 0.f;
    for (int cri=0; cri<16; cri++){
      int tt = cri*32 + cgj;
      s  += red[tt*8+q];
      sq += red[tt*8+4+q];
    }
    partial[(size_t)blockIdx.x*256 + t]       = s;
    partial[(size_t)blockIdx.x*256 + 128 + t] = sq;
  }
}

__global__ __launch_bounds__(256) void out_kernel(const float* __restrict__ hid,
                                                  const float* __restrict__ scale, const float* __restrict__ shift,
                                                  const float* __restrict__ outW, const float* __restrict__ outb,
                                                  float* __restrict__ out){
  int c = blockIdx.x*4 + (threadIdx.x >> 6);
  int l = threadIdx.x & 63;
  float v = softplusf_(hid[(size_t)c*128 + l]*scale[l] + shift[l])*outW[l]
          + softplusf_(hid[(size_t)c*128 + 64 + l]*scale[64+l] + shift[64+l])*outW[64+l];
  for (int off=32; off; off >>= 1) v += __shfl_down(v, off);
  if (l == 0) out[c] = v + outb[0];
}

// ---------------------------------------------------------------- launch
extern "C" void kernel_launch(void* const* d_in, const int* in_sizes, int n_in,
                              void* d_out, int out_size, void* d_ws, size_t ws_size,
                              hipStream_t stream){
  const float* aw    = (const float*)d_in[0];
  const float* orig  = (const float*)d_in[1];
  const float* nbr   = (const float*)d_in[2];
  const int*   sidx  = (const int*)d_in[3];
  const int*   nidx  = (const int*)d_in[4];
  const int*   cry   = (const int*)d_in[5];
  const float* embW  = (const float*)d_in[6];
  const float* embB  = (const float*)d_in[7];
  const float* filtW = (const float*)d_in[8];
  const float* filtB = (const float*)d_in[9];
  const float* coreW = (const float*)d_in[10];
  const float* coreB = (const float*)d_in[11];
  const float* bnfg  = (const float*)d_in[12];
  const float* bnfb  = (const float*)d_in[13];
  const float* bncg  = (const float*)d_in[14];
  const float* bncb  = (const float*)d_in[15];
  const float* bnog  = (const float*)d_in[16];
  const float* bnob  = (const float*)d_in[17];
  const float* gW1   = (const float*)d_in[18];
  const float* gb1   = (const float*)d_in[19];
  const float* gbng  = (const float*)d_in[20];
  const float* gbnb  = (const float*)d_in[21];
  const float* gW2   = (const float*)d_in[22];
  const float* gb2   = (const float*)d_in[23];
  const float* fcW   = (const float*)d_in[24];
  const float* fcb   = (const float*)d_in[25];
  const float* fcbng = (const float*)d_in[26];
  const float* fcbnb = (const float*)d_in[27];
  const float* outW  = (const float*)d_in[28];
  const float* outb  = (const float*)d_in[29];
  float* out = (float*)d_out;

  float* ws      = (float*)d_ws;
  float* meanacc = ws;                              // N*64  (reused as hbuf)
  float* cnt     = meanacc + (size_t)NATOM*64;      // N (recip, fallback only)
  float* gate    = cnt     + NATOM;                 // N
  float* gmaxk   = gate    + NATOM;                 // C
  float* gsum    = gmaxk   + NCRY;                  // C (adjacent to gmaxk -> 1 memset)
  float* crys    = gsum    + NCRY;                  // C*64
  float* hid     = crys    + (size_t)NCRY*64;       // C*128
  float* part2   = hid     + (size_t)NCRY*128;      // 32*256
  float* scale   = part2   + 32*256;                // 128
  float* shift   = scale   + 128;                   // 128
  short* wth     = (short*)(shift + 128);           // 3*128*160
  short* wtl     = wth + 3*128*160;
  float* partial = (float*)(wtl + 3*128*160);       // 4096*256 floats (4 MB)
  short* atom_h  = (short*)(partial + 4096*256);    // N*64 shorts
  short* atom_l  = atom_h + (size_t)NATOM*64;       // N*64 shorts
  short* weh     = atom_l + (size_t)NATOM*64;       // 64*224 shorts
  short* wel     = weh + 64*224;                    // 64*224 shorts
  short* feap    = wel + 64*224;                    // M*32 shorts (permuted fea, bf16)
  int*   cnti    = (int*)(feap + (size_t)MEDGE*32); // N
  int*   ctr     = cnti + NATOM;                    // N (adjacent to cnti -> 1 memset)
  int*   loc     = ctr + NATOM;                     // N
  int*   base    = loc + NATOM;                     // N
  int*   bsum    = base + NATOM;                    // 1024
  int*   sidx_s  = bsum + 1024;                     // M
  int*   nidx_s  = sidx_s + MEDGE;                  // M
  unsigned short* ycache = (unsigned short*)(nidx_s + MEDGE);  // M*128 fp16 (268 MB, optional)
  size_t need = (size_t)((char*)(ycache + (size_t)MEDGE*128) - (char*)d_ws);
  bool use_yc = (ws_size >= need);
  unsigned short* yc = use_yc ? ycache : nullptr;
  (void)in_sizes; (void)n_in; (void)out_size;

  // prep: histogram + scan + sort-by-self + weight prep + embedding
  hipMemsetAsync(cnti, 0, 2*NATOM*sizeof(int), stream);   // cnti + ctr
  hist_kernel<<<2048, 256, 0, stream>>>(sidx, cnti);
  scan1<<<NATOM/256, 256, 0, stream>>>(cnti, loc, bsum);
  scan2<<<1, 256, 0, stream>>>(bsum);
  scan3<<<NATOM/256, 256, 0, stream>>>(loc, bsum, base);
  wprep<<<240, 256, 0, stream>>>(filtW, coreW, wth, wtl);
  wprep_embed<<<56, 256, 0, stream>>>(embW, weh, wel);
  rank_kernel<<<2048, 256, 0, stream>>>(sidx, nidx, base, ctr, nbr, sidx_s, nidx_s, feap);
  embed_mfma<<<NATOM/64, 256, 0, stream>>>(orig, weh, wel, embB, atom_h, atom_l);
  if (!use_yc) recip_int<<<NATOM/256, 256, 0, stream>>>(cnti, cnt);

  // message-passing layers (sorted edge order)
  for (int i = 0; i < 3; ++i){
    const short* wthL = wth + (size_t)i*128*160;
    const short* wtlL = wtl + (size_t)i*128*160;
    const float* bf = filtB + i*64;
    const float* bc = coreB + i*64;
    edge_mfma<0><<<4096, 256, 0, stream>>>(atom_h, atom_l, feap, sidx_s, nidx_s, wthL, wtlL, bf, bc,
                                           nullptr, nullptr, partial, nullptr, yc);
    colstage<<<CSB, 256, 0, stream>>>(partial, part2, 4096);
    bnfin2_kernel<<<1, 128, 0, stream>>>(1.0f/MEDGE, part2,
                                         bnfg+i*64, bnfb+i*64, bncg+i*64, bncb+i*64, scale, shift);
    if (use_yc){
      aggregate<<<NATOM/128, 256, 0, stream>>>(ycache, base, cnti, scale, shift, meanacc, partial);
      colstage<<<CSB, 256, 0, stream>>>(partial, part2, NATOM/128);
      bnfin_kernel<<<1, 64, 0, stream>>>(64, 1.0f/NATOM, part2, bnog+i*64, bnob+i*64, scale, shift);
      atom_update<0><<<2048, 256, 0, stream>>>(atom_h, atom_l, meanacc, cnt, scale, shift);
    } else {
      hipMemsetAsync(meanacc, 0, (size_t)NATOM*64*sizeof(float), stream);
      edge_mfma<1><<<4096, 256, 0, stream>>>(atom_h, atom_l, feap, sidx_s, nidx_s, wthL, wtlL, bf, bc,
                                             scale, shift, nullptr, meanacc, nullptr);
      meanbn_stats<<<2048, 256, 0, stream>>>(cnt, meanacc, partial);
      colstage<<<CSB, 256, 0, stream>>>(partial, part2, 2048);
      bnfin_kernel<<<1, 64, 0, stream>>>(64, 1.0f/NATOM, part2, bnog+i*64, bnob+i*64, scale, shift);
      atom_update<1><<<2048, 256, 0, stream>>>(atom_h, atom_l, meanacc, cnt, scale, shift);
    }
  }

  // gate MLP + BN + attention pooling (hbuf reuses meanacc)
  float* hbuf = meanacc;
  gate_pass1<<<NATOM/256, 256, 0, stream>>>(atom_h, atom_l, gW1, gb1, hbuf, partial);
  colstage<<<CSB, 256, 0, stream>>>(partial, part2, NATOM/256);
  bnfin_kernel<<<1, 16, 0, stream>>>(16, 1.0f/NATOM, part2, gbng, gbnb, scale, shift);
  hipMemsetAsync(gmaxk, 0, 2*NCRY*sizeof(float), stream);   // gmaxk + gsum
  gate_pass2<<<NATOM/256, 256, 0, stream>>>(hbuf, scale, shift, gW2, gb2, cry, gate, (unsigned*)gmaxk);
  gate_exp<<<NATOM/256, 256, 0, stream>>>(gate, aw, cry, (const unsigned*)gmaxk, gsum);
  hipMemsetAsync(crys, 0, (size_t)NCRY*64*sizeof(float), stream);
  crys_acc<<<4096, 256, 0, stream>>>(gate, gsum, cry, atom_h, atom_l, crys);

  // fc head
  fc_stats<<<1024, 512, 0, stream>>>(crys, fcW, fcb, hid, partial);
  colstage<<<CSB, 256, 0, stream>>>(partial, part2, 1024);
  bnfin_kernel<<<1, 128, 0, stream>>>(128, 1.0f/NCRY, part2, fcbng, fcbnb, scale, shift);
  out_kernel<<<NCRY/4, 256, 0, stream>>>(hid, scale, shift, outW, outb, out);
}

// Round 21
// 1364.970 us; speedup vs baseline: 1.1914x; 1.0301x over previous
//
#include <hip/hip_runtime.h>
#include <hip/hip_fp16.h>
#include <cstdint>
#include <cstddef>

// Problem constants (from reference)
#define NATOM 262144
#define MEDGE 1048576
#define NCRY  32768
// ORIG=200, AF=64, NF=32, GH=16, H=128, NG=3

typedef __attribute__((ext_vector_type(8))) short short8v;   // 8 bf16 (4 VGPR)
typedef __attribute__((ext_vector_type(4))) float f32x4;     // MFMA acc

__device__ __forceinline__ float4 ld4(const float* p){ return *reinterpret_cast<const float4*>(p); }

__device__ __forceinline__ float softplusf_(float x){
  return fmaxf(x, 0.0f) + log1pf(expf(-fabsf(x)));
}
__device__ __forceinline__ float softplus_fast(float x){
  return fmaxf(x, 0.0f) + __logf(1.0f + __expf(-fabsf(x)));
}
__device__ __forceinline__ float sigmoid_fast(float y){
  return __builtin_amdgcn_rcpf(1.0f + __expf(-y));
}

__device__ __forceinline__ unsigned short rne_bf16(float f){
  unsigned u = __float_as_uint(f);
  unsigned r = u + 0x7FFFu + ((u >> 16) & 1u);
  return (unsigned short)(r >> 16);
}
__device__ __forceinline__ float bfu(unsigned short s){
  return __uint_as_float(((unsigned)s) << 16);
}

// monotonic float<->uint key for atomicMax-based segment max
__device__ __forceinline__ unsigned fkey(float x){
  unsigned b = __float_as_uint(x);
  return (b & 0x80000000u) ? ~b : (b | 0x80000000u);
}
__device__ __forceinline__ float fkeyinv(unsigned k){
  unsigned b = (k & 0x80000000u) ? (k & 0x7fffffffu) : ~k;
  return __uint_as_float(b);
}

// async global->LDS 16B copy (dest: wave-uniform base + lane*16 implicit)
__device__ __forceinline__ void gll16(const void* g, void* l){
  __builtin_amdgcn_global_load_lds((const __attribute__((address_space(1))) unsigned*)g,
                                   (__attribute__((address_space(3))) unsigned*)l, 16, 0, 0);
}

// RNE hi/lo split: a ~= bfu(h) + bfu(l)
__device__ __forceinline__ void rne_split(float a, unsigned short& h, unsigned short& l){
  h = rne_bf16(a);
  l = rne_bf16(a - bfu(h));
}

__device__ __forceinline__ unsigned short f2h(float a){
  __half hv = __float2half_rn(a);
  return *(unsigned short*)&hv;
}
__device__ __forceinline__ float h2f(unsigned short u){
  __half hv = *(__half*)&u;
  return __half2float(hv);
}

// ---------------------------------------------------------------- stats staging
#define CSB 32
__global__ __launch_bounds__(256) void colstage(const float* __restrict__ part,
                                                float* __restrict__ part2, int nb){
  int t = threadIdx.x;
  int rpb = nb / CSB;
  const float* p = part + (size_t)blockIdx.x*rpb*256 + t;
  float s = 0.f;
  #pragma unroll 4
  for (int r = 0; r < rpb; ++r) s += p[(size_t)r*256];
  part2[blockIdx.x*256 + t] = s;
}

// ---------------------------------------------------------------- edge sort by self atom (counting sort)
__global__ __launch_bounds__(256) void hist_kernel(const int* __restrict__ sidx, int* __restrict__ cnti){
  for (int m = blockIdx.x*256 + threadIdx.x; m < MEDGE; m += gridDim.x*256)
    atomicAdd(&cnti[sidx[m]], 1);
}

__global__ __launch_bounds__(256) void scan1(const int* __restrict__ cnti,
                                             int* __restrict__ loc, int* __restrict__ bsum){
  __shared__ int sm[256];
  int t = threadIdx.x;
  int v = cnti[blockIdx.x*256 + t];
  sm[t] = v;
  __syncthreads();
  for (int off = 1; off < 256; off <<= 1){
    int x = (t >= off) ? sm[t-off] : 0;
    __syncthreads();
    sm[t] += x;
    __syncthreads();
  }
  loc[blockIdx.x*256 + t] = sm[t] - v;     // exclusive
  if (t == 255) bsum[blockIdx.x] = sm[255];
}

__global__ __launch_bounds__(256) void scan2(int* __restrict__ bsum){
  __shared__ int sm[256];
  int t = threadIdx.x;
  int v0 = bsum[t*4+0], v1 = bsum[t*4+1], v2 = bsum[t*4+2], v3 = bsum[t*4+3];
  int tot = v0+v1+v2+v3;
  sm[t] = tot;
  __syncthreads();
  for (int off = 1; off < 256; off <<= 1){
    int x = (t >= off) ? sm[t-off] : 0;
    __syncthreads();
    sm[t] += x;
    __syncthreads();
  }
  int te = sm[t] - tot;
  bsum[t*4+0] = te;
  bsum[t*4+1] = te + v0;
  bsum[t*4+2] = te + v0 + v1;
  bsum[t*4+3] = te + v0 + v1 + v2;
}

__global__ __launch_bounds__(256) void scan3(const int* __restrict__ loc, const int* __restrict__ bsum,
                                             int* __restrict__ base){
  int i = blockIdx.x*256 + threadIdx.x;
  base[i] = loc[i] + bsum[i >> 8];
}

__global__ __launch_bounds__(256) void recip_int(const int* __restrict__ cnti, float* __restrict__ recip){
  int n = blockIdx.x*256 + threadIdx.x;
  if (n < NATOM) recip[n] = 1.0f / fmaxf((float)cnti[n], 1.0f);
}

// rank & permute: sidx_s/nidx_s sorted by self atom; nbr fea converted bf16 + permuted
__global__ __launch_bounds__(256) void rank_kernel(const int* __restrict__ sidx, const int* __restrict__ nidx,
                                                   const int* __restrict__ base, int* __restrict__ ctr,
                                                   const float* __restrict__ nbr,
                                                   int* __restrict__ sidx_s, int* __restrict__ nidx_s,
                                                   short* __restrict__ feap){
  for (int m = blockIdx.x*256 + threadIdx.x; m < MEDGE; m += gridDim.x*256){
    int s = sidx[m];
    int p = base[s] + atomicAdd(&ctr[s], 1);
    sidx_s[p] = s;
    nidx_s[p] = nidx[m];
    const float* src = nbr + (size_t)m*32;
    uint4* dst = (uint4*)(feap + (size_t)p*32);
    #pragma unroll
    for (int c = 0; c < 4; ++c){
      float4 a = ld4(src + c*8), b = ld4(src + c*8 + 4);
      float fv[8] = {a.x,a.y,a.z,a.w,b.x,b.y,b.z,b.w};
      unsigned w[4];
      #pragma unroll
      for (int i=0;i<4;i++)
        w[i] = (unsigned)rne_bf16(fv[2*i]) | ((unsigned)rne_bf16(fv[2*i+1]) << 16);
      dst[c] = make_uint4(w[0],w[1],w[2],w[3]);
    }
  }
}

// ---------------------------------------------------------------- embed W prep
__global__ __launch_bounds__(256) void wprep_embed(const float* __restrict__ embW,
                                                   short* __restrict__ Weh, short* __restrict__ Wel){
  int idx = blockIdx.x*256 + threadIdx.x;   // 64*224 = 14336
  if (idx >= 64*224) return;
  int k = idx % 224, c = idx / 224;
  float w = (k < 200) ? embW[(size_t)k*64 + c] : 0.0f;
  unsigned short h, l;
  rne_split(w, h, l);
  Weh[idx] = (short)h;
  Wel[idx] = (short)l;
}

// ---------------------------------------------------------------- embedding via split-bf16 MFMA
__global__ __launch_bounds__(256) void embed_mfma(const float* __restrict__ orig,
                                                  const short* __restrict__ Weh,
                                                  const short* __restrict__ Wel,
                                                  const float* __restrict__ bias,
                                                  short* __restrict__ atom_h,
                                                  short* __restrict__ atom_l){
  __shared__ uint4 ab4[3208];   // 51328 B
  char* ab = (char*)ab4;
  int t = threadIdx.x, lane = t & 63, wid = t >> 6;
  int r16 = lane & 15, g = lane >> 4;
  int col = wid*16 + r16;

  short8v Bh[7], Bl[7];
  #pragma unroll
  for (int ks = 0; ks < 7; ks++){
    int o = col*224 + ks*32 + g*8;
    Bh[ks] = *(const short8v*)(Weh + o);
    Bl[ks] = *(const short8v*)(Wel + o);
  }
  float bv = bias[col];
  int n0 = blockIdx.x * 64;
  const char* src = (const char*)orig + (size_t)n0*800;
  #pragma unroll
  for (int i = 0; i < 13; i++){
    int j = wid + i*4;
    if (j < 50) gll16(src + j*1024 + lane*16, ab + j*1024);
  }
  __syncthreads();

  #pragma unroll
  for (int grp = 0; grp < 4; grp++){
    f32x4 acc = {bv, bv, bv, bv};
    const char* arow = ab + (grp*16 + r16)*800;
    #pragma unroll
    for (int ks = 0; ks < 7; ks++){
      short8v ah, al;
      if (ks < 6 || g == 0){
        const float* f = (const float*)(arow + ks*128 + g*32);
        float4 f0 = *(const float4*)f, f1 = *(const float4*)(f+4);
        float fv[8] = {f0.x,f0.y,f0.z,f0.w,f1.x,f1.y,f1.z,f1.w};
        unsigned hw[4], lw[4];
        #pragma unroll
        for (int p = 0; p < 4; p++){
          unsigned short h0, l0, h1, l1;
          rne_split(fv[2*p], h0, l0);
          rne_split(fv[2*p+1], h1, l1);
          hw[p] = (unsigned)h0 | ((unsigned)h1 << 16);
          lw[p] = (unsigned)l0 | ((unsigned)l1 << 16);
        }
        ah = __builtin_bit_cast(short8v, make_uint4(hw[0],hw[1],hw[2],hw[3]));
        al = __builtin_bit_cast(short8v, make_uint4(lw[0],lw[1],lw[2],lw[3]));
      } else {
        ah = (short8v)0; al = (short8v)0;
      }
      acc = __builtin_amdgcn_mfma_f32_16x16x32_bf16(ah, Bh[ks], acc, 0, 0, 0);
      acc = __builtin_amdgcn_mfma_f32_16x16x32_bf16(al, Bh[ks], acc, 0, 0, 0);
      acc = __builtin_amdgcn_mfma_f32_16x16x32_bf16(ah, Bl[ks], acc, 0, 0, 0);
    }
    int rowb = n0 + grp*16 + g*4;
    #pragma unroll
    for (int r = 0; r < 4; r++){
      float a = acc[r];
      unsigned short h, l;
      rne_split(a, h, l);
      size_t off = (size_t)(rowb + r)*64 + col;
      atom_h[off] = (short)h;
      atom_l[off] = (short)l;
    }
  }
}

// ---------------------------------------------------------------- W prep (edge)
__global__ __launch_bounds__(256) void wprep(const float* __restrict__ filtW, const float* __restrict__ coreW,
                                             short* __restrict__ Wth, short* __restrict__ Wtl){
  int idx = blockIdx.x*256 + threadIdx.x;   // 3*128*160 = 61440
  if (idx >= 3*128*160) return;
  int k = idx % 160; int rest = idx / 160; int c = rest & 127; int layer = rest >> 7;
  float w = (c < 64) ? filtW[((size_t)layer*160 + k)*64 + c] : coreW[((size_t)layer*160 + k)*64 + (c-64)];
  unsigned short h, l;
  rne_split(w, h, l);
  Wth[idx] = (short)h;
  Wtl[idx] = (short)l;
}

// ---------------------------------------------------------------- edge GEMM: 2-phase gll pipeline, TILE=32
// LDS: 28 cols x 32 edges x 16B = 14KB/buffer (28KB total -> 5 blocks/CU).
// cols: 0-7 self_h, 8-15 nbr_h, 16-19 fea, 20-27 self_l  (nbr lo + fea lo dropped, RNE-unbiased).
// PASS0 optionally writes ycache fp16: unit8B idx = (e>>2)*128 + col, elem (e&3).
#define NT_PER_BLK 8

#define MFMA_B(A,B,ACC) ACC = __builtin_amdgcn_mfma_f32_16x16x32_bf16(A, B, ACC, 0, 0, 0)

template<int PASS>
__global__ __launch_bounds__(256) void edge_mfma(
    const short* __restrict__ atom_h, const short* __restrict__ atom_l,
    const short* __restrict__ nbr_h,
    const int* __restrict__ sidx, const int* __restrict__ nidx,
    const short* __restrict__ Wth, const short* __restrict__ Wtl,
    const float* __restrict__ bfp, const float* __restrict__ bcp,
    const float* __restrict__ scale, const float* __restrict__ shift,
    float* __restrict__ partial,
    float* __restrict__ meanacc,
    unsigned short* __restrict__ ycache)
{
  __shared__ uint4 xb[2][28*32];   // 2 x 14 KB
  int t = threadIdx.x, lane = t & 63, wid = t >> 6;   // 4 waves
  int r16 = lane & 15, g = lane >> 4;
  int colf = wid*16 + r16, colc = colf + 64;
  int el = lane & 31;

  short8v Bhf[5], Blf[5], Bhc[5], Blc[5];
  {
    const short* wfh = Wth + colf*160;
    const short* wch = Wth + colc*160;
    const short* wfl = Wtl + colf*160;
    const short* wcl = Wtl + colc*160;
    #pragma unroll
    for (int ks = 0; ks < 5; ks++){
      int o = ks*32 + g*8;
      Bhf[ks] = *(const short8v*)(wfh + o);
      Bhc[ks] = *(const short8v*)(wch + o);
      Blf[ks] = *(const short8v*)(wfl + o);
      Blc[ks] = *(const short8v*)(wcl + o);
    }
  }
  float bfv = bfp[colf], bcv = bcp[colf];
  float sf = 0.f, hf = 0.f, sc = 0.f, hc = 0.f;
  if (PASS == 1){ sf = scale[colf]; hf = shift[colf]; sc = scale[colc]; hc = shift[colc]; }
  float s0 = 0.f, q0 = 0.f, s1 = 0.f, q1 = 0.f;

  int tile0 = blockIdx.x * NT_PER_BLK;

  #define STAGE(BUF, TILE, SE, NE)                                              \
  {                                                                             \
    uint4* dst = (uint4*)(BUF);                                                 \
    int e0s_ = (TILE)*32;                                                       \
    _Pragma("unroll")                                                           \
    for (int j = wid; j < 14; j += 4){                                          \
      int c = 2*j + (lane >> 5);                                                \
      const short* src;                                                         \
      if      (c < 8)  src = atom_h + (size_t)(SE)*64 + c*8;                    \
      else if (c < 16) src = atom_h + (size_t)(NE)*64 + (c-8)*8;                \
      else if (c < 20) src = nbr_h + (size_t)(e0s_+el)*32 + (c-16)*8;           \
      else             src = atom_l + (size_t)(SE)*64 + (c-20)*8;               \
      gll16(src, dst + j*64);                                                   \
    }                                                                           \
  }

  int se, ne;
  { int e = tile0*32 + el; se = sidx[e]; ne = nidx[e]; }
  STAGE(xb[0], tile0, se, ne);
  { int e = (tile0+1)*32 + el; se = sidx[e]; ne = nidx[e]; }

  for (int tt = 0; tt < NT_PER_BLK; ++tt){
    asm volatile("s_waitcnt vmcnt(0)" ::: "memory");
    __builtin_amdgcn_s_barrier();           // LDS tile tt ready for all waves
    if (tt+1 < NT_PER_BLK){
      STAGE(xb[(tt+1)&1], tile0+tt+1, se, ne);
      if (tt+2 < NT_PER_BLK){ int e = (tile0+tt+2)*32 + el; se = sidx[e]; ne = nidx[e]; }
    }
    int e0 = (tile0+tt)*32;
    const char* buf = (const char*)xb[tt & 1];
    #pragma unroll
    for (int grp = 0; grp < 2; ++grp){
      f32x4 accf = {bfv,bfv,bfv,bfv}, accc = {bcv,bcv,bcv,bcv};
      const char* base = buf + (grp*16 + r16)*16;
      #pragma unroll
      for (int ks = 0; ks < 5; ++ks){
        short8v ah = *(const short8v*)(base + (ks*4+g)*512);
        MFMA_B(ah, Bhf[ks], accf); MFMA_B(ah, Bhc[ks], accc);
        MFMA_B(ah, Blf[ks], accf); MFMA_B(ah, Blc[ks], accc);
        if (ks < 2){
          short8v al = *(const short8v*)(base + (20+ks*4+g)*512);
          MFMA_B(al, Bhf[ks], accf); MFMA_B(al, Bhc[ks], accc);
        }
      }
      if (PASS == 0){
        #pragma unroll
        for (int r = 0; r < 4; r++){
          float yf = accf[r], yc = accc[r];
          s0 += yf; q0 += yf*yf; s1 += yc; q1 += yc*yc;
        }
        if (ycache){
          int ebase = e0 + grp*16 + g*4;         // 4 consecutive edges, 4-aligned
          uint2 pf, pc;
          #pragma unroll
          for (int r = 0; r < 4; r++){
            ((__half*)&pf)[r] = __float2half_rn(accf[r]);
            ((__half*)&pc)[r] = __float2half_rn(accc[r]);
          }
          uint2* yrow = (uint2*)ycache + (size_t)(ebase >> 2)*128;
          yrow[colf]      = pf;
          yrow[64 + colf] = pc;
        }
      } else {
        // sorted edges: run-compress atomics (thread's 4 edges are consecutive)
        int ebase = e0 + grp*16 + g*4;
        int a_prev = sidx[ebase];
        float accum = 0.f;
        #pragma unroll
        for (int r = 0; r < 4; r++){
          float f  = sigmoid_fast(accf[r]*sf + hf);
          float c2 = softplus_fast(accc[r]*sc + hc);
          int a = sidx[ebase + r];
          if (a != a_prev){
            atomicAdd(&meanacc[(size_t)a_prev*64 + colf], accum);
            accum = 0.f;
            a_prev = a;
          }
          accum += f*c2;
        }
        atomicAdd(&meanacc[(size_t)a_prev*64 + colf], accum);
      }
    }
  }
  #undef STAGE

  if (PASS == 0){
    s0 += __shfl_xor(s0,16); s0 += __shfl_xor(s0,32);
    q0 += __shfl_xor(q0,16); q0 += __shfl_xor(q0,32);
    s1 += __shfl_xor(s1,16); s1 += __shfl_xor(s1,32);
    q1 += __shfl_xor(q1,16); q1 += __shfl_xor(q1,32);
    __syncthreads();
    float* scm = (float*)&xb[0][0];
    if (g == 0)
      *(float4*)&scm[(wid*16 + r16)*4] = make_float4(s0, q0, s1, q1);
    __syncthreads();
    {
      int stat = t >> 7, colx = t & 127;
      int isc = (colx >= 64) ? 1 : 0;
      int cc = colx & 63;
      int v = isc*2 + stat;
      partial[(size_t)blockIdx.x*256 + stat*128 + colx] = scm[((cc>>4)*16 + (cc&15))*4 + v];
    }
  }
}

// ---------------------------------------------------------------- fused segment-mean (fp16 out) + BN-o stats
__global__ __launch_bounds__(256) void aggregate(const unsigned short* __restrict__ ycache,
                                                 const int* __restrict__ base,
                                                 const int* __restrict__ cnti,
                                                 const float* __restrict__ scale,
                                                 const float* __restrict__ shift,
                                                 unsigned short* __restrict__ meanh,
                                                 float* __restrict__ partial){
  int t = threadIdx.x, j = t & 63, w = t >> 6;
  float sf = scale[j], hf = shift[j];
  float sc = scale[j+64], hc = shift[j+64];
  float s = 0.f, q = 0.f;
  int n0 = blockIdx.x*128 + w*32;        // grid 2048 -> 128 atoms/block, 32/wave
  for (int i = 0; i < 32; ++i){
    int n = n0 + i;
    int b0 = base[n], deg = cnti[n];
    float acc = 0.f;
    if (deg > 0){
      int q0 = b0 >> 2, q1 = (b0 + deg + 3) >> 2;
      for (int qq = q0; qq < q1; ++qq){
        const uint2* yrow = (const uint2*)ycache + (size_t)qq*128;
        uint2 f4 = yrow[j], c4 = yrow[64 + j];
        int e0 = qq*4;
        #pragma unroll
        for (int r = 0; r < 4; ++r){
          int e = e0 + r;
          if (e >= b0 && e < b0 + deg){
            float yf = __half2float(((const __half*)&f4)[r]);
            float yc = __half2float(((const __half*)&c4)[r]);
            acc += sigmoid_fast(yf*sf + hf) * softplus_fast(yc*sc + hc);
          }
        }
      }
    }
    float mean = acc / fmaxf((float)deg, 1.0f);
    meanh[(size_t)n*64 + j] = f2h(mean);
    s += mean; q += mean*mean;
  }
  __shared__ float red[4][128];
  red[w][j] = s; red[w][64+j] = q;
  __syncthreads();
  if (t < 64){
    partial[(size_t)blockIdx.x*256 + t]       = red[0][t]+red[1][t]+red[2][t]+red[3][t];
    partial[(size_t)blockIdx.x*256 + 128 + t] = red[0][64+t]+red[1][64+t]+red[2][64+t]+red[3][64+t];
  }
}

// ---------------------------------------------------------------- BN finalize (reads part2)
__global__ void bnfin_kernel(int nf, float invcnt, const float* __restrict__ p2,
                             const float* __restrict__ g, const float* __restrict__ b,
                             float* __restrict__ scale, float* __restrict__ shift){
  int j = threadIdx.x;
  if (j >= nf) return;
  float s = 0.f, q = 0.f;
  #pragma unroll 4
  for (int r = 0; r < CSB; ++r){
    s += p2[r*256 + j];
    q += p2[r*256 + 128 + j];
  }
  float m = s*invcnt;
  float v = fmaxf(q*invcnt - m*m, 0.0f);
  float is = rsqrtf(v + 1e-5f);
  float sc = g[j]*is;
  scale[j] = sc;
  shift[j] = b[j] - m*sc;
}

__global__ void bnfin2_kernel(float invcnt, const float* __restrict__ p2,
                              const float* __restrict__ g0, const float* __restrict__ b0,
                              const float* __restrict__ g1, const float* __restrict__ b1,
                              float* __restrict__ scale, float* __restrict__ shift){
  int j = threadIdx.x;   // 128
  float s = 0.f, q = 0.f;
  #pragma unroll 4
  for (int r = 0; r < CSB; ++r){
    s += p2[r*256 + j];
    q += p2[r*256 + 128 + j];
  }
  float m = s*invcnt;
  float v = fmaxf(q*invcnt - m*m, 0.0f);
  float is = rsqrtf(v + 1e-5f);
  float gg = (j < 64) ? g0[j] : g1[j-64];
  float bb = (j < 64) ? b0[j] : b1[j-64];
  float sc = gg*is;
  scale[j] = sc;
  shift[j] = bb - m*sc;
}

// ---------------------------------------------------------------- stats of mean = meanacc * recip (fallback path)
__global__ __launch_bounds__(256) void meanbn_stats(const float* __restrict__ recip,
                                                    const float* __restrict__ meanacc,
                                                    float* __restrict__ partial){
  int t = threadIdx.x;
  float s = 0.f, q = 0.f;
  for (size_t idx = (size_t)blockIdx.x*256 + t; idx < (size_t)NATOM*64; idx += (size_t)gridDim.x*256){
    int n = (int)(idx >> 6);
    float v = meanacc[idx]*recip[n];
    s += v; q += v*v;
  }
  __shared__ float red[256][2];
  red[t][0]=s; red[t][1]=q;
  __syncthreads();
  if (t < 64){
    for (int i=1;i<4;i++){ s += red[t+64*i][0]; q += red[t+64*i][1]; }
    partial[(size_t)blockIdx.x*256 + t]       = s;
    partial[(size_t)blockIdx.x*256 + 128 + t] = q;
  }
}

// atom = softplus(atom + mean*scale + shift); fp16 mean input (ycache path), 4 cols/thread
__global__ __launch_bounds__(256) void atom_update_h(short* __restrict__ atom_h,
                                                     short* __restrict__ atom_l,
                                                     const unsigned short* __restrict__ meanh,
                                                     const float* __restrict__ scale,
                                                     const float* __restrict__ shift){
  for (size_t idx = (size_t)blockIdx.x*256 + threadIdx.x; idx < (size_t)NATOM*16; idx += (size_t)gridDim.x*256){
    int n = (int)(idx >> 4), c4 = (int)(idx & 15)*4;
    size_t off = (size_t)n*64 + c4;
    uint2 mh = *(const uint2*)(meanh + off);
    uint2 hh = *(const uint2*)(atom_h + off);
    uint2 ll = *(const uint2*)(atom_l + off);
    unsigned short ms[4] = {(unsigned short)(mh.x & 0xFFFF), (unsigned short)(mh.x >> 16),
                            (unsigned short)(mh.y & 0xFFFF), (unsigned short)(mh.y >> 16)};
    unsigned short hs[4] = {(unsigned short)(hh.x & 0xFFFF), (unsigned short)(hh.x >> 16),
                            (unsigned short)(hh.y & 0xFFFF), (unsigned short)(hh.y >> 16)};
    unsigned short ls[4] = {(unsigned short)(ll.x & 0xFFFF), (unsigned short)(ll.x >> 16),
                            (unsigned short)(ll.y & 0xFFFF), (unsigned short)(ll.y >> 16)};
    unsigned oh[4], ol[4];
    #pragma unroll
    for (int r = 0; r < 4; ++r){
      float prev = bfu(hs[r]) + bfu(ls[r]);
      float a = softplus_fast(prev + h2f(ms[r])*scale[c4+r] + shift[c4+r]);
      unsigned short h, l;
      rne_split(a, h, l);
      oh[r] = h; ol[r] = l;
    }
    *(uint2*)(atom_h + off) = make_uint2(oh[0] | (oh[1] << 16), oh[2] | (oh[3] << 16));
    *(uint2*)(atom_l + off) = make_uint2(ol[0] | (ol[1] << 16), ol[2] | (ol[3] << 16));
  }
}

// fallback: fp32 mean with premul recip
__global__ __launch_bounds__(256) void atom_update_f(short* __restrict__ atom_h,
                                                     short* __restrict__ atom_l,
                                                     const float* __restrict__ meanacc,
                                                     const float* __restrict__ recip,
                                                     const float* __restrict__ scale,
                                                     const float* __restrict__ shift){
  for (size_t idx = (size_t)blockIdx.x*256 + threadIdx.x; idx < (size_t)NATOM*16; idx += (size_t)gridDim.x*256){
    int n = (int)(idx >> 4), c4 = (int)(idx & 15)*4;
    size_t off = (size_t)n*64 + c4;
    float4 mv = ld4(meanacc + off);
    float rc = recip[n];
    uint2 hh = *(const uint2*)(atom_h + off);
    uint2 ll = *(const uint2*)(atom_l + off);
    float m4[4] = {mv.x, mv.y, mv.z, mv.w};
    unsigned short hs[4] = {(unsigned short)(hh.x & 0xFFFF), (unsigned short)(hh.x >> 16),
                            (unsigned short)(hh.y & 0xFFFF), (unsigned short)(hh.y >> 16)};
    unsigned short ls[4] = {(unsigned short)(ll.x & 0xFFFF), (unsigned short)(ll.x >> 16),
                            (unsigned short)(ll.y & 0xFFFF), (unsigned short)(ll.y >> 16)};
    unsigned oh[4], ol[4];
    #pragma unroll
    for (int r = 0; r < 4; ++r){
      float prev = bfu(hs[r]) + bfu(ls[r]);
      float a = softplus_fast(prev + m4[r]*rc*scale[c4+r] + shift[c4+r]);
      unsigned short h, l;
      rne_split(a, h, l);
      oh[r] = h; ol[r] = l;
    }
    *(uint2*)(atom_h + off) = make_uint2(oh[0] | (oh[1] << 16), oh[2] | (oh[3] << 16));
    *(uint2*)(atom_l + off) = make_uint2(ol[0] | (ol[1] << 16), ol[2] | (ol[3] << 16));
  }
}

// ---------------------------------------------------------------- gate MLP, pass 1
__global__ __launch_bounds__(256, 2) void gate_pass1(const short* __restrict__ atom_h,
                                                     const short* __restrict__ atom_l,
                                                     const float* __restrict__ W1, const float* __restrict__ b1,
                                                     float* __restrict__ hbuf,
                                                     float* __restrict__ partial){
  __shared__ float As[256*65];   // 66.6 KB
  __shared__ float Wl[64*16];
  int t = threadIdx.x;
  *(float4*)&Wl[t*4] = ld4(W1 + t*4);
  const short* hsrc = atom_h + (size_t)blockIdx.x*256*64;
  const short* lsrc = atom_l + (size_t)blockIdx.x*256*64;
  #pragma unroll
  for (int j = 0; j < 8; j++){
    int idx = j*256 + t;
    uint4 hv = *(const uint4*)(hsrc + idx*8);
    uint4 lv = *(const uint4*)(lsrc + idx*8);
    int r = idx >> 3, c = (idx & 7)*8;
    float* d = &As[r*65 + c];
    unsigned hw[4] = {hv.x,hv.y,hv.z,hv.w}, lw[4] = {lv.x,lv.y,lv.z,lv.w};
    #pragma unroll
    for (int i = 0; i < 4; i++){
      d[2*i]   = __uint_as_float(hw[i] << 16)          + __uint_as_float(lw[i] << 16);
      d[2*i+1] = __uint_as_float(hw[i] & 0xFFFF0000u)  + __uint_as_float(lw[i] & 0xFFFF0000u);
    }
  }
  __syncthreads();
  float h[16];
  #pragma unroll
  for (int c=0;c<16;c++) h[c] = b1[c];
  const float* ar = &As[t*65];
  #pragma unroll 8
  for (int k=0;k<64;k++){
    float a = ar[k];
    #pragma unroll
    for (int c=0;c<16;c++) h[c] += a*Wl[k*16+c];
  }
  size_t n = (size_t)blockIdx.x*256 + t;
  #pragma unroll
  for (int c=0;c<16;c+=4)
    *(float4*)&hbuf[n*16+c] = make_float4(h[c],h[c+1],h[c+2],h[c+3]);
  __syncthreads();
  #pragma unroll
  for (int c=0;c<16;c++){
    float v = h[c], v2 = h[c]*h[c];
    for (int off=32; off; off>>=1){ v += __shfl_down(v,off); v2 += __shfl_down(v2,off); }
    if ((t&63)==0){ As[(t>>6)*32 + c] = v; As[(t>>6)*32 + 16 + c] = v2; }
  }
  __syncthreads();
  if (t < 32){
    float v = As[t] + As[32+t] + As[64+t] + As[96+t];
    int col = (t < 16) ? t : (128 + t - 16);
    partial[(size_t)blockIdx.x*256 + col] = v;
  }
}

// ---------------------------------------------------------------- gate MLP, pass 2
__global__ __launch_bounds__(256) void gate_pass2(const float* __restrict__ hbuf,
                                                  const float* __restrict__ scale, const float* __restrict__ shift,
                                                  const float* __restrict__ W2, const float* __restrict__ b2,
                                                  const int* __restrict__ cry,
                                                  float* __restrict__ gate, unsigned* __restrict__ gmaxk){
  int n = blockIdx.x*256 + threadIdx.x;
  float g = b2[0];
  #pragma unroll
  for (int c=0;c<16;c+=4){
    float4 hv = ld4(hbuf + (size_t)n*16 + c);
    float4 sc = ld4(scale + c), sh = ld4(shift + c), w = ld4(W2 + c);
    g += fmaxf(hv.x*sc.x+sh.x,0.f)*w.x + fmaxf(hv.y*sc.y+sh.y,0.f)*w.y
       + fmaxf(hv.z*sc.z+sh.z,0.f)*w.z + fmaxf(hv.w*sc.w+sh.w,0.f)*w.w;
  }
  gate[n] = g;
  atomicMax(&gmaxk[cry[n]], fkey(g));
}

__global__ __launch_bounds__(256) void gate_exp(float* __restrict__ gate,
                                                const float* __restrict__ aw,
                                                const int* __restrict__ cry,
                                                const unsigned* __restrict__ gmaxk,
                                                float* __restrict__ gsum){
  int n = blockIdx.x*256 + threadIdx.x;
  if (n < NATOM){
    int c = cry[n];
    float w = aw[n]*expf(gate[n] - fkeyinv(gmaxk[c]));
    gate[n] = w;
    atomicAdd(&gsum[c], w);
  }
}

// per-column: wave = one atom's 64 cols (distinct addresses, no same-address conflicts)
__global__ __launch_bounds__(256) void crys_acc(const float* __restrict__ gate,
                                                const float* __restrict__ gsum,
                                                const int* __restrict__ cry,
                                                const short* __restrict__ atom_h,
                                                const short* __restrict__ atom_l,
                                                float* __restrict__ crys){
  for (size_t idx = (size_t)blockIdx.x*256 + threadIdx.x; idx < (size_t)NATOM*64; idx += (size_t)gridDim.x*256){
    int n = (int)(idx >> 6), j = (int)(idx & 63);
    int c = cry[n];
    float wn = gate[n] / (gsum[c] + 1e-13f);
    float a = bfu((unsigned short)atom_h[idx]) + bfu((unsigned short)atom_l[idx]);
    atomicAdd(&crys[(size_t)c*64 + j], wn*a);
  }
}

// ---------------------------------------------------------------- fc head
__global__ __launch_bounds__(512) void fc_stats(const float* __restrict__ crys,
                                                const float* __restrict__ fcW, const float* __restrict__ fcb,
                                                float* __restrict__ hid,
                                                float* __restrict__ partial){
  __shared__ float Wl[64*128];
  __shared__ float cb[64][16];
  int t = threadIdx.x;
  for (int j = t; j < 64*32; j += 512)
    *(float4*)&Wl[j*4] = ld4(fcW + j*4);
  int cg = t & 31, cr = t >> 5;
  float4 bias = ld4(fcb + cg*4);
  float ssum[4] = {0,0,0,0}, ssq[4] = {0,0,0,0};
  for (int chunk = blockIdx.x; chunk < NCRY/16; chunk += gridDim.x){
    int c0 = chunk*16;
    __syncthreads();
    for (int j = t; j < 256; j += 512){
      int rr = j & 15, c = j >> 4;
      float4 v = ld4(crys + (size_t)(c0+rr)*64 + c*4);
      int k = c*4;
      cb[k][rr]=v.x; cb[k+1][rr]=v.y; cb[k+2][rr]=v.z; cb[k+3][rr]=v.w;
    }
    __syncthreads();
    float4 acc = bias;
    #pragma unroll 4
    for (int k=0;k<64;k++){
      float a = cb[k][cr];
      float4 w = *(float4*)&Wl[k*128 + cg*4];
      acc.x += a*w.x; acc.y += a*w.y; acc.z += a*w.z; acc.w += a*w.w;
    }
    *(float4*)&hid[(size_t)(c0+cr)*128 + cg*4] = acc;
    ssum[0]+=acc.x; ssum[1]+=acc.y; ssum[2]+=acc.z; ssum[3]+=acc.w;
    ssq[0]+=acc.x*acc.x; ssq[1]+=acc.y*acc.y; ssq[2]+=acc.z*acc.z; ssq[3]+=acc.w*acc.w;
  }
  __syncthreads();
  float* red = Wl;
  #pragma unroll
  for (int q=0;q<4;q++){ red[t*8+q] = ssum[q]; red[t*8+4+q] = ssq[q]; }
  __syncthreads();
  if (t < 128){
    int cgj = t >> 2, q = t & 3;
    float s = 0.f, sq = 0.f;
    for (int cri=0; cri<16; cri++){
      int tt = cri*32 + cgj;
      s  += red[tt*8+q];
      sq += red[tt*8+4+q];
    }
    partial[(size_t)blockIdx.x*256 + t]       = s;
    partial[(size_t)blockIdx.x*256 + 128 + t] = sq;
  }
}

__global__ __launch_bounds__(256) void out_kernel(const float* __restrict__ hid,
                                                  const float* __restrict__ scale, const float* __restrict__ shift,
                                                  const float* __restrict__ outW, const float* __restrict__ outb,
                                                  float* __restrict__ out){
  int c = blockIdx.x*4 + (threadIdx.x >> 6);
  int l = threadIdx.x & 63;
  float v = softplusf_(hid[(size_t)c*128 + l]*scale[l] + shift[l])*outW[l]
          + softplusf_(hid[(size_t)c*128 + 64 + l]*scale[64+l] + shift[64+l])*outW[64+l];
  for (int off=32; off; off >>= 1) v += __shfl_down(v, off);
  if (l == 0) out[c] = v + outb[0];
}

// ---------------------------------------------------------------- launch
extern "C" void kernel_launch(void* const* d_in, const int* in_sizes, int n_in,
                              void* d_out, int out_size, void* d_ws, size_t ws_size,
                              hipStream_t stream){
  const float* aw    = (const float*)d_in[0];
  const float* orig  = (const float*)d_in[1];
  const float* nbr   = (const float*)d_in[2];
  const int*   sidx  = (const int*)d_in[3];
  const int*   nidx  = (const int*)d_in[4];
  const int*   cry   = (const int*)d_in[5];
  const float* embW  = (const float*)d_in[6];
  const float* embB  = (const float*)d_in[7];
  const float* filtW = (const float*)d_in[8];
  const float* filtB = (const float*)d_in[9];
  const float* coreW = (const float*)d_in[10];
  const float* coreB = (const float*)d_in[11];
  const float* bnfg  = (const float*)d_in[12];
  const float* bnfb  = (const float*)d_in[13];
  const float* bncg  = (const float*)d_in[14];
  const float* bncb  = (const float*)d_in[15];
  const float* bnog  = (const float*)d_in[16];
  const float* bnob  = (const float*)d_in[17];
  const float* gW1   = (const float*)d_in[18];
  const float* gb1   = (const float*)d_in[19];
  const float* gbng  = (const float*)d_in[20];
  const float* gbnb  = (const float*)d_in[21];
  const float* gW2   = (const float*)d_in[22];
  const float* gb2   = (const float*)d_in[23];
  const float* fcW   = (const float*)d_in[24];
  const float* fcb   = (const float*)d_in[25];
  const float* fcbng = (const float*)d_in[26];
  const float* fcbnb = (const float*)d_in[27];
  const float* outW  = (const float*)d_in[28];
  const float* outb  = (const float*)d_in[29];
  float* out = (float*)d_out;

  float* ws      = (float*)d_ws;
  float* meanacc = ws;                              // N*64 fp32 (fallback) / N*64 fp16 (yc path) ; reused as hbuf
  float* cnt     = meanacc + (size_t)NATOM*64;      // N (recip, fallback only)
  float* gate    = cnt     + NATOM;                 // N
  float* gmaxk   = gate    + NATOM;                 // C
  float* gsum    = gmaxk   + NCRY;                  // C (adjacent to gmaxk -> 1 memset)
  float* crys    = gsum    + NCRY;                  // C*64
  float* hid     = crys    + (size_t)NCRY*64;       // C*128
  float* part2   = hid     + (size_t)NCRY*128;      // 32*256
  float* scale   = part2   + 32*256;                // 128
  float* shift   = scale   + 128;                   // 128
  short* wth     = (short*)(shift + 128);           // 3*128*160
  short* wtl     = wth + 3*128*160;
  float* partial = (float*)(wtl + 3*128*160);       // 4096*256 floats (4 MB)
  short* atom_h  = (short*)(partial + 4096*256);    // N*64 shorts
  short* atom_l  = atom_h + (size_t)NATOM*64;       // N*64 shorts
  short* weh     = atom_l + (size_t)NATOM*64;       // 64*224 shorts
  short* wel     = weh + 64*224;                    // 64*224 shorts
  short* feap    = wel + 64*224;                    // M*32 shorts (permuted fea, bf16)
  int*   cnti    = (int*)(feap + (size_t)MEDGE*32); // N
  int*   ctr     = cnti + NATOM;                    // N (adjacent to cnti -> 1 memset)
  int*   loc     = ctr + NATOM;                     // N
  int*   base    = loc + NATOM;                     // N
  int*   bsum    = base + NATOM;                    // 1024
  int*   sidx_s  = bsum + 1024;                     // M
  int*   nidx_s  = sidx_s + MEDGE;                  // M
  unsigned short* ycache = (unsigned short*)(nidx_s + MEDGE);  // M*128 fp16 (268 MB, optional)
  size_t need = (size_t)((char*)(ycache + (size_t)MEDGE*128) - (char*)d_ws);
  bool use_yc = (ws_size >= need);
  unsigned short* yc = use_yc ? ycache : nullptr;
  unsigned short* meanh = (unsigned short*)meanacc;   // fp16 mean aliases meanacc region
  (void)in_sizes; (void)n_in; (void)out_size;

  // prep: histogram + scan + sort-by-self + weight prep + embedding
  hipMemsetAsync(cnti, 0, 2*NATOM*sizeof(int), stream);   // cnti + ctr
  hist_kernel<<<2048, 256, 0, stream>>>(sidx, cnti);
  scan1<<<NATOM/256, 256, 0, stream>>>(cnti, loc, bsum);
  scan2<<<1, 256, 0, stream>>>(bsum);
  scan3<<<NATOM/256, 256, 0, stream>>>(loc, bsum, base);
  wprep<<<240, 256, 0, stream>>>(filtW, coreW, wth, wtl);
  wprep_embed<<<56, 256, 0, stream>>>(embW, weh, wel);
  rank_kernel<<<2048, 256, 0, stream>>>(sidx, nidx, base, ctr, nbr, sidx_s, nidx_s, feap);
  embed_mfma<<<NATOM/64, 256, 0, stream>>>(orig, weh, wel, embB, atom_h, atom_l);
  if (!use_yc) recip_int<<<NATOM/256, 256, 0, stream>>>(cnti, cnt);

  // message-passing layers (sorted edge order)
  for (int i = 0; i < 3; ++i){
    const short* wthL = wth + (size_t)i*128*160;
    const short* wtlL = wtl + (size_t)i*128*160;
    const float* bf = filtB + i*64;
    const float* bc = coreB + i*64;
    edge_mfma<0><<<4096, 256, 0, stream>>>(atom_h, atom_l, feap, sidx_s, nidx_s, wthL, wtlL, bf, bc,
                                           nullptr, nullptr, partial, nullptr, yc);
    colstage<<<CSB, 256, 0, stream>>>(partial, part2, 4096);
    bnfin2_kernel<<<1, 128, 0, stream>>>(1.0f/MEDGE, part2,
                                         bnfg+i*64, bnfb+i*64, bncg+i*64, bncb+i*64, scale, shift);
    if (use_yc){
      aggregate<<<NATOM/128, 256, 0, stream>>>(ycache, base, cnti, scale, shift, meanh, partial);
      colstage<<<CSB, 256, 0, stream>>>(partial, part2, NATOM/128);
      bnfin_kernel<<<1, 64, 0, stream>>>(64, 1.0f/NATOM, part2, bnog+i*64, bnob+i*64, scale, shift);
      atom_update_h<<<2048, 256, 0, stream>>>(atom_h, atom_l, meanh, scale, shift);
    } else {
      hipMemsetAsync(meanacc, 0, (size_t)NATOM*64*sizeof(float), stream);
      edge_mfma<1><<<4096, 256, 0, stream>>>(atom_h, atom_l, feap, sidx_s, nidx_s, wthL, wtlL, bf, bc,
                                             scale, shift, nullptr, meanacc, nullptr);
      meanbn_stats<<<2048, 256, 0, stream>>>(cnt, meanacc, partial);
      colstage<<<CSB, 256, 0, stream>>>(partial, part2, 2048);
      bnfin_kernel<<<1, 64, 0, stream>>>(64, 1.0f/NATOM, part2, bnog+i*64, bnob+i*64, scale, shift);
      atom_update_f<<<2048, 256, 0, stream>>>(atom_h, atom_l, meanacc, cnt, scale, shift);
    }
  }

  // gate MLP + BN + attention pooling (hbuf reuses meanacc)
  float* hbuf = meanacc;
  gate_pass1<<<NATOM/256, 256, 0, stream>>>(atom_h, atom_l, gW1, gb1, hbuf, partial);
  colstage<<<CSB, 256, 0, stream>>>(partial, part2, NATOM/256);
  bnfin_kernel<<<1, 16, 0, stream>>>(16, 1.0f/NATOM, part2, gbng, gbnb, scale, shift);
  hipMemsetAsync(gmaxk, 0, 2*NCRY*sizeof(float), stream);   // gmaxk + gsum
  gate_pass2<<<NATOM/256, 256, 0, stream>>>(hbuf, scale, shift, gW2, gb2, cry, gate, (unsigned*)gmaxk);
  gate_exp<<<NATOM/256, 256, 0, stream>>>(gate, aw, cry, (const unsigned*)gmaxk, gsum);
  hipMemsetAsync(crys, 0, (size_t)NCRY*64*sizeof(float), stream);
  crys_acc<<<4096, 256, 0, stream>>>(gate, gsum, cry, atom_h, atom_l, crys);

  // fc head
  fc_stats<<<1024, 512, 0, stream>>>(crys, fcW, fcb, hid, partial);
  colstage<<<CSB, 256, 0, stream>>>(partial, part2, 1024);
  bnfin_kernel<<<1, 128, 0, stream>>>(128, 1.0f/NCRY, part2, fcbng, fcbnb, scale, shift);
  out_kernel<<<NCRY/4, 256, 0, stream>>>(hid, scale, shift, outW, outb, out);
}